// Round 5
// baseline (961.926 us; speedup 1.0000x reference)
//
#include <hip/hip_runtime.h>

typedef __attribute__((ext_vector_type(8))) short short8;
typedef __attribute__((ext_vector_type(4))) float floatx4;
typedef __attribute__((ext_vector_type(8))) int int8v;

__device__ __forceinline__ float bf2f(unsigned short u) {
    union { unsigned int i; float f; } c; c.i = ((unsigned int)u) << 16; return c.f;
}
__device__ __forceinline__ float asf(unsigned int u) {
    union { unsigned int i; float f; } c; c.i = u; return c.f;
}
__device__ __forceinline__ unsigned short f2bf(float f) {
    union { float f; unsigned int i; } c; c.f = f;
    unsigned int u = c.i;
    return (unsigned short)((u + 0x7FFFu + ((u >> 16) & 1u)) >> 16);
}
__device__ __forceinline__ unsigned short f2bf_rz(float f) {
    union { float f; unsigned int i; } c; c.f = f;
    return (unsigned short)(c.i >> 16);
}
__device__ __forceinline__ float sigm(float x) {
    return __builtin_amdgcn_rcpf(1.f + __expf(-x));
}
__device__ __forceinline__ float tanh_(float x) {
    return 1.f - 2.f * __builtin_amdgcn_rcpf(1.f + __expf(2.f * x));
}

__device__ __forceinline__ void glds16(const void* g, void* l) {
    __builtin_amdgcn_global_load_lds((const __attribute__((address_space(1))) unsigned int*)g,
                                     (__attribute__((address_space(3))) unsigned int*)l, 16, 0, 0);
}

// ---------------- cast weights to bf16 (w_ih_f | w_ih_b | w_fc) ----------------
__global__ void k_cast_weights(const float* __restrict__ wihf, const float* __restrict__ wihb,
                               const float* __restrict__ wfc, unsigned short* __restrict__ dst) {
    int i = blockIdx.x * 256 + threadIdx.x;
    if (i >= 532480) return;
    float v;
    if (i < 262144) v = wihf[i];
    else if (i < 524288) v = wihb[i - 262144];
    else v = wfc[i - 524288];
    dst[i] = f2bf(v);
}

// ---------------- cast w_hh (f|b) to fp8 e4m3 ----------------
__global__ void k_cast_fp8(const float* __restrict__ whhf, const float* __restrict__ whhb,
                           unsigned char* __restrict__ dst) {
    int i = blockIdx.x * 256 + threadIdx.x;   // 262144 threads, 2 elems each
    if (i >= 262144) return;
    int e = i * 2;
    float a = (e < 262144) ? whhf[e] : whhb[e - 262144];
    float b = (e + 1 < 262144) ? whhf[e + 1] : whhb[e + 1 - 262144];
    int p = __builtin_amdgcn_cvt_pk_fp8_f32(a, b, 0, false);
    *(unsigned short*)(dst + e) = (unsigned short)(p & 0xffff);
}

// ---------------- embedding gather -> e_t[t*64+b][256] bf16 ----------------
__global__ void k_gather(const int* __restrict__ x, const float* __restrict__ emb,
                         unsigned short* __restrict__ et) {
    int id = blockIdx.x * 256 + threadIdx.x;   // 1,048,576 total
    int m = id >> 5, fi = (id & 31) << 3;
    int b = m & 63, t = m >> 6;
    int v = x[b * 512 + t];
    const float4* s = (const float4*)(emb + ((size_t)v << 8) + fi);
    float4 a = s[0], q = s[1];
    uint4 o;
    o.x = (unsigned)f2bf(a.x) | ((unsigned)f2bf(a.y) << 16);
    o.y = (unsigned)f2bf(a.z) | ((unsigned)f2bf(a.w) << 16);
    o.z = (unsigned)f2bf(q.x) | ((unsigned)f2bf(q.y) << 16);
    o.w = (unsigned)f2bf(q.z) | ((unsigned)f2bf(q.w) << 16);
    *(uint4*)(et + ((size_t)m << 8) + fi) = o;
}

// ---------------- gx = e @ w_ih.T + b, both dirs (N=2048) ----------------
// Output layout: [d][t][b][unit*4 + gate] bf16 (gate-interleaved so k_lstm loads 1 dwordx2)
__global__ __launch_bounds__(256, 2) void k_gx(const unsigned short* __restrict__ et,
                                               const unsigned short* __restrict__ wcat,
                                               const float* __restrict__ bfv, const float* __restrict__ bbv,
                                               unsigned short* __restrict__ gx) {
    __shared__ unsigned short As[4096];
    __shared__ unsigned short Bs[4096];
    const int tid = threadIdx.x;
    const int w = tid >> 6, l = tid & 63, quad = l >> 4, col = l & 15;
    const size_t m0 = (size_t)blockIdx.x * 128, n0 = (size_t)blockIdx.y * 128;
    floatx4 C[4][4];
    #pragma unroll
    for (int i = 0; i < 4; ++i)
        #pragma unroll
        for (int j = 0; j < 4; ++j) C[i][j] = (floatx4){0.f, 0.f, 0.f, 0.f};
    const int srow = tid >> 2, scol = (tid & 3) * 16;
    for (int it = 0; it < 8; ++it) {
        const char* ga = (const char*)et + (m0 + srow) * 512 + it * 64 + scol;
        const char* gb = (const char*)wcat + (n0 + srow) * 512 + it * 64 + scol;
        glds16(ga,             (char*)As + w * 1024);
        glds16(ga + 64 * 512,  (char*)As + 4096 + w * 1024);
        glds16(gb,             (char*)Bs + w * 1024);
        glds16(gb + 64 * 512,  (char*)Bs + 4096 + w * 1024);
        __syncthreads();
        short8 Af[4], Bf[4];
        #pragma unroll
        for (int i = 0; i < 4; ++i) {
            Af[i] = *(const short8*)(As + (((w & 1) * 64 + i * 16 + col) * 32 + quad * 8));
            Bf[i] = *(const short8*)(Bs + (((w >> 1) * 64 + i * 16 + col) * 32 + quad * 8));
        }
        #pragma unroll
        for (int i = 0; i < 4; ++i)
            #pragma unroll
            for (int j = 0; j < 4; ++j)
                C[i][j] = __builtin_amdgcn_mfma_f32_16x16x32_bf16(Af[i], Bf[j], C[i][j], 0, 0, 0);
        __syncthreads();
    }
    const int mw = (w & 1) * 64, nw = (w >> 1) * 64;
    #pragma unroll
    for (int j = 0; j < 4; ++j) {
        int n = (int)n0 + nw + j * 16 + col;
        float bias = (n < 1024) ? bfv[n] : bbv[n - 1024];
        // gate-interleaved: element index = unit*4 + gate
        size_t dbase = (size_t)(n >> 10) * 33554432 + (size_t)(((n & 255) << 2) | ((n >> 8) & 3));
        #pragma unroll
        for (int i = 0; i < 4; ++i)
            #pragma unroll
            for (int r = 0; r < 4; ++r) {
                size_t m = m0 + mw + i * 16 + quad * 4 + r;
                gx[dbase + m * 1024] = f2bf(C[i][j][r] + bias);
            }
    }
}

// ---------------- LSTM recurrence: 64 wgs = 2 dirs x 32 batch-groups of 2; 512 thr (8 waves) ----
// Swapped-operand MFMA: A = h (fp8), B = W fragments. Batch lives in A-row BLOCKS of 8
// (rows 0-7 = b0, 8-15 = b1) so C batch = quad>>1 for ANY r => z[g] = nts ? C[g][1][0] : C[g][0][0]
// (4 cndmask total). Lane owns (b = l>>5, u = 32w + (l&31)). g-outer MFMA ordering exposes
// early-gate VALU under later-gate MFMAs. gx is gate-interleaved: one dwordx2 per step.
__global__ __launch_bounds__(512, 2) void k_lstm(const unsigned char* __restrict__ w8_all,
                                                 const unsigned short* __restrict__ gx_all,
                                                 unsigned short* __restrict__ hcat) {
    const int d = blockIdx.x >> 5, bg = blockIdx.x & 31;
    const int tid = threadIdx.x, w = tid >> 6, l = tid & 63, quad = l >> 4, col = l & 15;
    const unsigned char* W = w8_all + (size_t)d * 262144;
    const unsigned short* G = gx_all + (size_t)d * 33554432;
    __shared__ __align__(16) unsigned char hld[2][2][288]; // 1,152 B  h fp8 [buf][batch][unit]

    // B-fragments (W): Wb[g][nt][kt] holds W[256g + 32w + 16nt + col][kt*128 + quad*32 .. +31]
    int8v Wb[4][2][2];
    #pragma unroll
    for (int g = 0; g < 4; ++g)
        #pragma unroll
        for (int nt = 0; nt < 2; ++nt)
            #pragma unroll
            for (int kt = 0; kt < 2; ++kt)
                Wb[g][nt][kt] = *(const int8v*)(W + (size_t)(256 * g + 32 * w + 16 * nt + col) * 256
                                                + kt * 128 + quad * 32);
    for (int i = tid; i < 288; i += 512) ((unsigned int*)hld)[i] = 0;

    const int b = l >> 5, u = 32 * w + (l & 31);           // this lane's (batch, unit)
    const int bglob = 2 * bg + b;
    const int nts = quad & 1;                              // nt select for z extraction
    const int hsel = (l >> 3) & 1;                         // batch block for A-fragment rows
    float cst = 0.f;
    const long gstep = d ? -65536 : 65536;                 // shorts per t in gx
    const long hstep = d ? -32768 : 32768;                 // shorts per t in hcat
    const unsigned short* gp = G + ((size_t)((d ? 511 : 0) * 64 + bglob) * 1024 + u * 4);
    unsigned short* hp = hcat + ((size_t)((d ? 511 : 0) * 64 + bglob) * 512 + d * 256 + u);
    uint2 gq = *(const uint2*)gp;                          // gates i,f (x) g,o (y) for this unit
    gp += gstep;
    __syncthreads();

    #pragma clang loop unroll(disable)
    for (int step = 0; step < 512; ++step) {
        const int cur = step & 1;
        // ---- MFMA phase: A = h (row blocks of 8 per batch), B = W; g-outer for early z ----
        int8v Af[2];
        #pragma unroll
        for (int kt = 0; kt < 2; ++kt)
            Af[kt] = *(const int8v*)(&hld[cur][hsel][kt * 128 + quad * 32]);
        float z[4];
        #pragma unroll
        for (int g = 0; g < 4; ++g) {
            floatx4 c0 = (floatx4){0.f, 0.f, 0.f, 0.f};
            floatx4 c1 = (floatx4){0.f, 0.f, 0.f, 0.f};
            #pragma unroll
            for (int kt = 0; kt < 2; ++kt) {
                c0 = __builtin_amdgcn_mfma_scale_f32_16x16x128_f8f6f4(
                    Af[kt], Wb[g][0][kt], c0, 0, 0, 0, 0x7f7f7f7f, 0, 0x7f7f7f7f);
                c1 = __builtin_amdgcn_mfma_scale_f32_16x16x128_f8f6f4(
                    Af[kt], Wb[g][1][kt], c1, 0, 0, 0, 0x7f7f7f7f, 0, 0x7f7f7f7f);
            }
            z[g] = nts ? c1[0] : c0[0];
        }
        // ---- gate phase: fully distributed, one (batch,unit) per lane ----
        float vi = z[0] + asf(gq.x << 16);
        float vf = z[1] + asf(gq.x & 0xffff0000u);
        float vg = z[2] + asf(gq.y << 16);
        float vo = z[3] + asf(gq.y & 0xffff0000u);
        // prefetch next step's gx (stays in flight across the raw barrier)
        gq = *(const uint2*)gp;
        gp += gstep;
        float cc = sigm(vf) * cst + sigm(vi) * tanh_(vg);
        cst = cc;
        float hf = sigm(vo) * tanh_(cc);
        *hp = f2bf_rz(hf);
        hp += hstep;
        int pk = __builtin_amdgcn_cvt_pk_fp8_f32(hf, hf, 0, false);
        hld[cur ^ 1][b][u] = (unsigned char)(pk & 0xff);
        // ---- step boundary: LDS-only drain + raw barrier (no vmcnt drain) ----
        __builtin_amdgcn_sched_barrier(0);
        asm volatile("s_waitcnt lgkmcnt(0)");
        __builtin_amdgcn_sched_barrier(0);
        __builtin_amdgcn_s_barrier();
        __builtin_amdgcn_sched_barrier(0);
    }
}

// ---------------- scores = hcat @ w_fc.T + b_fc, fp32 [t][b][32] ----------------
__global__ __launch_bounds__(256, 4) void k_scores(const unsigned short* __restrict__ hcat,
                                                   const unsigned short* __restrict__ wfc,
                                                   const float* __restrict__ bfc,
                                                   float* __restrict__ sc) {
    const int tid = threadIdx.x, w = tid >> 6, l = tid & 63, quad = l >> 4, col = l & 15;
    const int m0 = blockIdx.x * 64 + w * 16;
    floatx4 C0 = (floatx4){0.f, 0.f, 0.f, 0.f}, C1 = C0;
    #pragma unroll
    for (int kt = 0; kt < 16; ++kt) {
        short8 A  = *(const short8*)(hcat + (size_t)(m0 + col) * 512 + kt * 32 + quad * 8);
        short8 B0 = *(const short8*)(wfc + (size_t)col * 512 + kt * 32 + quad * 8);
        short8 B1 = *(const short8*)(wfc + (size_t)(16 + col) * 512 + kt * 32 + quad * 8);
        C0 = __builtin_amdgcn_mfma_f32_16x16x32_bf16(A, B0, C0, 0, 0, 0);
        C1 = __builtin_amdgcn_mfma_f32_16x16x32_bf16(A, B1, C1, 0, 0, 0);
    }
    float b0 = bfc[col], b1 = bfc[16 + col];
    #pragma unroll
    for (int r = 0; r < 4; ++r) {
        int m = m0 + quad * 4 + r;
        sc[(size_t)m * 32 + col] = C0[r] + b0;
        sc[(size_t)m * 32 + 16 + col] = C1[r] + b1;
    }
}

// ---------------- CRF: true path score + forward algorithm, loss += total - true ----------------
// Double-buffered alpha: ONE barrier per t-step; sc/mask prefetched one step ahead.
__global__ __launch_bounds__(1024, 1) void k_crf(const float* __restrict__ sc, const int* __restrict__ tags,
                                                 const int* __restrict__ mask, const float* __restrict__ tr,
                                                 float* __restrict__ out) {
    __shared__ float Tm[32][33];
    __shared__ float al[2][32];
    __shared__ float trueb;
    const int b = blockIdx.x, tid = threadIdx.x;
    { int i = tid >> 5, j = tid & 31; Tm[i][j] = tr[tid]; }
    __syncthreads();
    if (tid < 64) {
        float acc = 0.f; int cnt = 0;
        for (int t = tid; t < 512; t += 64) cnt += mask[b * 512 + t];
        for (int t = tid + 1; t < 512; t += 64) {
            if (mask[b * 512 + t]) {
                int tg = tags[b * 512 + t], tp = tags[b * 512 + t - 1];
                acc += Tm[tp][tg] + sc[((size_t)t * 64 + b) * 32 + tg];
            }
        }
        #pragma unroll
        for (int m = 1; m < 64; m <<= 1) { acc += __shfl_xor(acc, m); cnt += __shfl_xor(cnt, m); }
        if (tid == 0) {
            int tg0 = tags[b * 512];
            float first = Tm[30][tg0] + sc[(size_t)b * 32 + tg0];
            int lt = tags[b * 512 + cnt - 1];
            trueb = first + acc + Tm[lt][31];
        }
    }
    if (tid < 32) al[0][tid] = Tm[30][tid] + sc[(size_t)b * 32 + tid];
    __syncthreads();
    const int j = tid >> 5, i = tid & 31;
    int cur = 0;
    float scn = sc[((size_t)64 + b) * 32 + j];
    int mkn = mask[b * 512 + 1];
    #pragma clang loop unroll(disable)
    for (int t = 1; t < 512; ++t) {
        float v = al[cur][i] + Tm[i][j];
        float mx = v;
        #pragma unroll
        for (int m = 1; m < 32; m <<= 1) mx = fmaxf(mx, __shfl_xor(mx, m));
        float e = __expf(v - mx);
        #pragma unroll
        for (int m = 1; m < 32; m <<= 1) e += __shfl_xor(e, m);
        float nv = mx + __logf(e) + scn;
        int mk = mkn;
        int tn = t < 511 ? t + 1 : 511;
        scn = sc[((size_t)tn * 64 + b) * 32 + j];
        mkn = mask[b * 512 + tn];
        if (i == 0) al[cur ^ 1][j] = mk ? nv : al[cur][j];
        __syncthreads();
        cur ^= 1;
    }
    if (tid < 32) {
        float v = al[cur][tid] + Tm[tid][31];
        float mx = v;
        #pragma unroll
        for (int m = 1; m < 32; m <<= 1) mx = fmaxf(mx, __shfl_xor(mx, m));
        float e = __expf(v - mx);
        #pragma unroll
        for (int m = 1; m < 32; m <<= 1) e += __shfl_xor(e, m);
        if (tid == 0) atomicAdd(out, mx + __logf(e) - trueb);
    }
}

extern "C" void kernel_launch(void* const* d_in, const int* in_sizes, int n_in,
                              void* d_out, int out_size, void* d_ws, size_t ws_size,
                              hipStream_t stream) {
    const int* x      = (const int*)d_in[0];
    const int* tags   = (const int*)d_in[1];
    const int* mask   = (const int*)d_in[2];
    const float* emb  = (const float*)d_in[3];
    const float* wihf = (const float*)d_in[4];
    const float* whhf = (const float*)d_in[5];
    const float* bf_  = (const float*)d_in[6];
    const float* wihb = (const float*)d_in[7];
    const float* whhb = (const float*)d_in[8];
    const float* bb_  = (const float*)d_in[9];
    const float* wfc  = (const float*)d_in[10];
    const float* bfc  = (const float*)d_in[11];
    const float* tr   = (const float*)d_in[12];

    char* ws = (char*)d_ws;
    unsigned short* et   = (unsigned short*)(ws);                 //  16,777,216 B
    unsigned short* wbf  = (unsigned short*)(ws + 16777216);      //   1,064,960 B (wih f|b cat, then wfc @ elem 524288)
    unsigned char*  w8   = (unsigned char*)(ws + 17842176);      //     524,288 B (whh f|b fp8)
    unsigned short* gx   = (unsigned short*)(ws + 18366464);      // 134,217,728 B
    unsigned short* hcat = (unsigned short*)(ws + 152584192);     //  33,554,432 B
    float* sc            = (float*)(ws + 186138624);              //   4,194,304 B

    hipMemsetAsync(d_out, 0, sizeof(float), stream);
    k_cast_weights<<<2080, 256, 0, stream>>>(wihf, wihb, wfc, wbf);
    k_cast_fp8<<<1024, 256, 0, stream>>>(whhf, whhb, w8);
    k_gather<<<4096, 256, 0, stream>>>(x, emb, et);
    dim3 g2(256, 16);
    k_gx<<<g2, 256, 0, stream>>>(et, wbf, bf_, bb_, gx);
    k_lstm<<<64, 512, 0, stream>>>(w8, gx, hcat);
    k_scores<<<512, 256, 0, stream>>>(hcat, wbf + 524288, bfc, sc);
    k_crf<<<64, 1024, 0, stream>>>(sc, tags, mask, tr, (float*)d_out);
}

// Round 6
// 909.812 us; speedup vs baseline: 1.0573x; 1.0573x over previous
//
#include <hip/hip_runtime.h>

typedef __attribute__((ext_vector_type(8))) short short8;
typedef __attribute__((ext_vector_type(4))) float floatx4;
typedef __attribute__((ext_vector_type(8))) int int8v;

__device__ __forceinline__ float bf2f(unsigned short u) {
    union { unsigned int i; float f; } c; c.i = ((unsigned int)u) << 16; return c.f;
}
__device__ __forceinline__ unsigned short f2bf(float f) {
    union { float f; unsigned int i; } c; c.f = f;
    unsigned int u = c.i;
    return (unsigned short)((u + 0x7FFFu + ((u >> 16) & 1u)) >> 16);
}
__device__ __forceinline__ unsigned short f2bf_rz(float f) {
    union { float f; unsigned int i; } c; c.f = f;
    return (unsigned short)(c.i >> 16);
}
__device__ __forceinline__ float sigm(float x) {
    return __builtin_amdgcn_rcpf(1.f + __expf(-x));
}
__device__ __forceinline__ float tanh_(float x) {
    return 1.f - 2.f * __builtin_amdgcn_rcpf(1.f + __expf(2.f * x));
}

__device__ __forceinline__ void glds16(const void* g, void* l) {
    __builtin_amdgcn_global_load_lds((const __attribute__((address_space(1))) unsigned int*)g,
                                     (__attribute__((address_space(3))) unsigned int*)l, 16, 0, 0);
}

// ---------------- cast weights to bf16 (w_ih_f | w_ih_b | w_fc) ----------------
__global__ void k_cast_weights(const float* __restrict__ wihf, const float* __restrict__ wihb,
                               const float* __restrict__ wfc, unsigned short* __restrict__ dst) {
    int i = blockIdx.x * 256 + threadIdx.x;
    if (i >= 532480) return;
    float v;
    if (i < 262144) v = wihf[i];
    else if (i < 524288) v = wihb[i - 262144];
    else v = wfc[i - 524288];
    dst[i] = f2bf(v);
}

// ---------------- cast w_hh (f|b) to fp8 e4m3 ----------------
__global__ void k_cast_fp8(const float* __restrict__ whhf, const float* __restrict__ whhb,
                           unsigned char* __restrict__ dst) {
    int i = blockIdx.x * 256 + threadIdx.x;   // 262144 threads, 2 elems each
    if (i >= 262144) return;
    int e = i * 2;
    float a = (e < 262144) ? whhf[e] : whhb[e - 262144];
    float b = (e + 1 < 262144) ? whhf[e + 1] : whhb[e + 1 - 262144];
    int p = __builtin_amdgcn_cvt_pk_fp8_f32(a, b, 0, false);
    *(unsigned short*)(dst + e) = (unsigned short)(p & 0xffff);
}

// ---------------- embedding gather -> e_t[t*64+b][256] bf16 ----------------
__global__ void k_gather(const int* __restrict__ x, const float* __restrict__ emb,
                         unsigned short* __restrict__ et) {
    int id = blockIdx.x * 256 + threadIdx.x;   // 1,048,576 total
    int m = id >> 5, fi = (id & 31) << 3;
    int b = m & 63, t = m >> 6;
    int v = x[b * 512 + t];
    const float4* s = (const float4*)(emb + ((size_t)v << 8) + fi);
    float4 a = s[0], q = s[1];
    uint4 o;
    o.x = (unsigned)f2bf(a.x) | ((unsigned)f2bf(a.y) << 16);
    o.y = (unsigned)f2bf(a.z) | ((unsigned)f2bf(a.w) << 16);
    o.z = (unsigned)f2bf(q.x) | ((unsigned)f2bf(q.y) << 16);
    o.w = (unsigned)f2bf(q.z) | ((unsigned)f2bf(q.w) << 16);
    *(uint4*)(et + ((size_t)m << 8) + fi) = o;
}

// ---------------- gx = e @ w_ih.T + b, both dirs (N=2048), output bf16 [d][t][b][1024] ----------------
__global__ __launch_bounds__(256, 2) void k_gx(const unsigned short* __restrict__ et,
                                               const unsigned short* __restrict__ wcat,
                                               const float* __restrict__ bfv, const float* __restrict__ bbv,
                                               unsigned short* __restrict__ gx) {
    __shared__ unsigned short As[4096];
    __shared__ unsigned short Bs[4096];
    const int tid = threadIdx.x;
    const int w = tid >> 6, l = tid & 63, quad = l >> 4, col = l & 15;
    const size_t m0 = (size_t)blockIdx.x * 128, n0 = (size_t)blockIdx.y * 128;
    floatx4 C[4][4];
    #pragma unroll
    for (int i = 0; i < 4; ++i)
        #pragma unroll
        for (int j = 0; j < 4; ++j) C[i][j] = (floatx4){0.f, 0.f, 0.f, 0.f};
    const int srow = tid >> 2, scol = (tid & 3) * 16;
    for (int it = 0; it < 8; ++it) {
        const char* ga = (const char*)et + (m0 + srow) * 512 + it * 64 + scol;
        const char* gb = (const char*)wcat + (n0 + srow) * 512 + it * 64 + scol;
        glds16(ga,             (char*)As + w * 1024);
        glds16(ga + 64 * 512,  (char*)As + 4096 + w * 1024);
        glds16(gb,             (char*)Bs + w * 1024);
        glds16(gb + 64 * 512,  (char*)Bs + 4096 + w * 1024);
        __syncthreads();
        short8 Af[4], Bf[4];
        #pragma unroll
        for (int i = 0; i < 4; ++i) {
            Af[i] = *(const short8*)(As + (((w & 1) * 64 + i * 16 + col) * 32 + quad * 8));
            Bf[i] = *(const short8*)(Bs + (((w >> 1) * 64 + i * 16 + col) * 32 + quad * 8));
        }
        #pragma unroll
        for (int i = 0; i < 4; ++i)
            #pragma unroll
            for (int j = 0; j < 4; ++j)
                C[i][j] = __builtin_amdgcn_mfma_f32_16x16x32_bf16(Af[i], Bf[j], C[i][j], 0, 0, 0);
        __syncthreads();
    }
    const int mw = (w & 1) * 64, nw = (w >> 1) * 64;
    #pragma unroll
    for (int j = 0; j < 4; ++j) {
        int n = (int)n0 + nw + j * 16 + col;
        float bias = (n < 1024) ? bfv[n] : bbv[n - 1024];
        size_t dbase = (size_t)(n >> 10) * 33554432 + (size_t)(n & 1023);
        #pragma unroll
        for (int i = 0; i < 4; ++i)
            #pragma unroll
            for (int r = 0; r < 4; ++r) {
                size_t m = m0 + mw + i * 16 + quad * 4 + r;
                gx[dbase + m * 1024] = f2bf(C[i][j][r] + bias);
            }
    }
}

// ---------------- LSTM recurrence: 64 wgs = 2 dirs x 32 batch-groups of 2; 512 thr (8 waves) ----
// Swapped-operand MFMA: A = h (fp8), B = W fragments. Batch lives in A-row BLOCKS of 8
// (rows 0-7 = b0, 8-15 = b1) so C batch = quad>>1 for ANY r => z[g] = nts ? C[g][1][0] : C[g][0][0]
// (4 cndmask total). Lane owns (b = l>>5, u = 32w + (l&31)). g-outer MFMA ordering exposes
// early-gate VALU under later-gate MFMAs. Loop-invariant Z4 feeds the first MFMA's C-operand
// (no per-step accumulator zero-init movs). ONE raw s_barrier per step, lgkm-only drain.
__global__ __launch_bounds__(512, 2) void k_lstm(const unsigned char* __restrict__ w8_all,
                                                 const unsigned short* __restrict__ gx_all,
                                                 unsigned short* __restrict__ hcat) {
    const int d = blockIdx.x >> 5, bg = blockIdx.x & 31;
    const int tid = threadIdx.x, w = tid >> 6, l = tid & 63, quad = l >> 4, col = l & 15;
    const unsigned char* W = w8_all + (size_t)d * 262144;
    const unsigned short* G = gx_all + (size_t)d * 33554432;
    __shared__ __align__(16) unsigned char hld[2][2][288]; // 1,152 B  h fp8 [buf][batch][unit]

    // B-fragments (W): Wb[g][nt][kt] holds W[256g + 32w + 16nt + col][kt*128 + quad*32 .. +31]
    int8v Wb[4][2][2];
    #pragma unroll
    for (int g = 0; g < 4; ++g)
        #pragma unroll
        for (int nt = 0; nt < 2; ++nt)
            #pragma unroll
            for (int kt = 0; kt < 2; ++kt)
                Wb[g][nt][kt] = *(const int8v*)(W + (size_t)(256 * g + 32 * w + 16 * nt + col) * 256
                                                + kt * 128 + quad * 32);
    for (int i = tid; i < 288; i += 512) ((unsigned int*)hld)[i] = 0;

    const int b = l >> 5, u = 32 * w + (l & 31);           // this lane's (batch, unit)
    const int bglob = 2 * bg + b;
    const int nts = quad & 1;                              // nt select for z extraction
    const int hsel = (l >> 3) & 1;                         // batch block for A-fragment rows
    float cst = 0.f;
    const long gstep = d ? -65536 : 65536;                 // shorts per t in gx
    const long hstep = d ? -32768 : 32768;                 // shorts per t in hcat
    const unsigned short* gp = G + ((size_t)((d ? 511 : 0) * 64 + bglob) * 1024 + u);
    unsigned short* hp = hcat + ((size_t)((d ? 511 : 0) * 64 + bglob) * 512 + d * 256 + u);
    unsigned short gq0 = gp[0], gq1 = gp[256], gq2 = gp[512], gq3 = gp[768];
    gp += gstep;
    const floatx4 Z4 = (floatx4){0.f, 0.f, 0.f, 0.f};      // persistent zero C-operand
    __syncthreads();

    #pragma clang loop unroll(disable)
    for (int step = 0; step < 512; ++step) {
        const int cur = step & 1;
        // ---- MFMA phase: A = h (row blocks of 8 per batch), B = W; g-outer for early z ----
        int8v Af[2];
        #pragma unroll
        for (int kt = 0; kt < 2; ++kt)
            Af[kt] = *(const int8v*)(&hld[cur][hsel][kt * 128 + quad * 32]);
        float z[4];
        #pragma unroll
        for (int g = 0; g < 4; ++g) {
            floatx4 c0 = __builtin_amdgcn_mfma_scale_f32_16x16x128_f8f6f4(
                Af[0], Wb[g][0][0], Z4, 0, 0, 0, 0x7f7f7f7f, 0, 0x7f7f7f7f);
            floatx4 c1 = __builtin_amdgcn_mfma_scale_f32_16x16x128_f8f6f4(
                Af[0], Wb[g][1][0], Z4, 0, 0, 0, 0x7f7f7f7f, 0, 0x7f7f7f7f);
            c0 = __builtin_amdgcn_mfma_scale_f32_16x16x128_f8f6f4(
                Af[1], Wb[g][0][1], c0, 0, 0, 0, 0x7f7f7f7f, 0, 0x7f7f7f7f);
            c1 = __builtin_amdgcn_mfma_scale_f32_16x16x128_f8f6f4(
                Af[1], Wb[g][1][1], c1, 0, 0, 0, 0x7f7f7f7f, 0, 0x7f7f7f7f);
            z[g] = nts ? c1[0] : c0[0];
        }
        // ---- gate phase: fully distributed, one (batch,unit) per lane ----
        float vi = z[0] + bf2f(gq0);
        float vf = z[1] + bf2f(gq1);
        float vg = z[2] + bf2f(gq2);
        float vo = z[3] + bf2f(gq3);
        // prefetch next step's gx (stays in flight across the raw barrier)
        gq0 = gp[0]; gq1 = gp[256]; gq2 = gp[512]; gq3 = gp[768];
        gp += gstep;
        float cc = sigm(vf) * cst + sigm(vi) * tanh_(vg);
        cst = cc;
        float hf = sigm(vo) * tanh_(cc);
        *hp = f2bf_rz(hf);
        hp += hstep;
        int pk = __builtin_amdgcn_cvt_pk_fp8_f32(hf, hf, 0, false);
        hld[cur ^ 1][b][u] = (unsigned char)(pk & 0xff);
        // ---- step boundary: LDS-only drain + raw barrier (no vmcnt drain) ----
        __builtin_amdgcn_sched_barrier(0);
        asm volatile("s_waitcnt lgkmcnt(0)");
        __builtin_amdgcn_sched_barrier(0);
        __builtin_amdgcn_s_barrier();
        __builtin_amdgcn_sched_barrier(0);
    }
}

// ---------------- scores = hcat @ w_fc.T + b_fc, fp32 [t][b][32] ----------------
__global__ __launch_bounds__(256, 4) void k_scores(const unsigned short* __restrict__ hcat,
                                                   const unsigned short* __restrict__ wfc,
                                                   const float* __restrict__ bfc,
                                                   float* __restrict__ sc) {
    const int tid = threadIdx.x, w = tid >> 6, l = tid & 63, quad = l >> 4, col = l & 15;
    const int m0 = blockIdx.x * 64 + w * 16;
    floatx4 C0 = (floatx4){0.f, 0.f, 0.f, 0.f}, C1 = C0;
    #pragma unroll
    for (int kt = 0; kt < 16; ++kt) {
        short8 A  = *(const short8*)(hcat + (size_t)(m0 + col) * 512 + kt * 32 + quad * 8);
        short8 B0 = *(const short8*)(wfc + (size_t)col * 512 + kt * 32 + quad * 8);
        short8 B1 = *(const short8*)(wfc + (size_t)(16 + col) * 512 + kt * 32 + quad * 8);
        C0 = __builtin_amdgcn_mfma_f32_16x16x32_bf16(A, B0, C0, 0, 0, 0);
        C1 = __builtin_amdgcn_mfma_f32_16x16x32_bf16(A, B1, C1, 0, 0, 0);
    }
    float b0 = bfc[col], b1 = bfc[16 + col];
    #pragma unroll
    for (int r = 0; r < 4; ++r) {
        int m = m0 + quad * 4 + r;
        sc[(size_t)m * 32 + col] = C0[r] + b0;
        sc[(size_t)m * 32 + 16 + col] = C1[r] + b1;
    }
}

// ---------------- CRF: true path score + forward algorithm, loss += total - true ----------------
// Double-buffered alpha: ONE barrier per t-step; sc/mask prefetched one step ahead.
__global__ __launch_bounds__(1024, 1) void k_crf(const float* __restrict__ sc, const int* __restrict__ tags,
                                                 const int* __restrict__ mask, const float* __restrict__ tr,
                                                 float* __restrict__ out) {
    __shared__ float Tm[32][33];
    __shared__ float al[2][32];
    __shared__ float trueb;
    const int b = blockIdx.x, tid = threadIdx.x;
    { int i = tid >> 5, j = tid & 31; Tm[i][j] = tr[tid]; }
    __syncthreads();
    if (tid < 64) {
        float acc = 0.f; int cnt = 0;
        for (int t = tid; t < 512; t += 64) cnt += mask[b * 512 + t];
        for (int t = tid + 1; t < 512; t += 64) {
            if (mask[b * 512 + t]) {
                int tg = tags[b * 512 + t], tp = tags[b * 512 + t - 1];
                acc += Tm[tp][tg] + sc[((size_t)t * 64 + b) * 32 + tg];
            }
        }
        #pragma unroll
        for (int m = 1; m < 64; m <<= 1) { acc += __shfl_xor(acc, m); cnt += __shfl_xor(cnt, m); }
        if (tid == 0) {
            int tg0 = tags[b * 512];
            float first = Tm[30][tg0] + sc[(size_t)b * 32 + tg0];
            int lt = tags[b * 512 + cnt - 1];
            trueb = first + acc + Tm[lt][31];
        }
    }
    if (tid < 32) al[0][tid] = Tm[30][tid] + sc[(size_t)b * 32 + tid];
    __syncthreads();
    const int j = tid >> 5, i = tid & 31;
    int cur = 0;
    float scn = sc[((size_t)64 + b) * 32 + j];
    int mkn = mask[b * 512 + 1];
    #pragma clang loop unroll(disable)
    for (int t = 1; t < 512; ++t) {
        float v = al[cur][i] + Tm[i][j];
        float mx = v;
        #pragma unroll
        for (int m = 1; m < 32; m <<= 1) mx = fmaxf(mx, __shfl_xor(mx, m));
        float e = __expf(v - mx);
        #pragma unroll
        for (int m = 1; m < 32; m <<= 1) e += __shfl_xor(e, m);
        float nv = mx + __logf(e) + scn;
        int mk = mkn;
        int tn = t < 511 ? t + 1 : 511;
        scn = sc[((size_t)tn * 64 + b) * 32 + j];
        mkn = mask[b * 512 + tn];
        if (i == 0) al[cur ^ 1][j] = mk ? nv : al[cur][j];
        __syncthreads();
        cur ^= 1;
    }
    if (tid < 32) {
        float v = al[cur][tid] + Tm[tid][31];
        float mx = v;
        #pragma unroll
        for (int m = 1; m < 32; m <<= 1) mx = fmaxf(mx, __shfl_xor(mx, m));
        float e = __expf(v - mx);
        #pragma unroll
        for (int m = 1; m < 32; m <<= 1) e += __shfl_xor(e, m);
        if (tid == 0) atomicAdd(out, mx + __logf(e) - trueb);
    }
}

extern "C" void kernel_launch(void* const* d_in, const int* in_sizes, int n_in,
                              void* d_out, int out_size, void* d_ws, size_t ws_size,
                              hipStream_t stream) {
    const int* x      = (const int*)d_in[0];
    const int* tags   = (const int*)d_in[1];
    const int* mask   = (const int*)d_in[2];
    const float* emb  = (const float*)d_in[3];
    const float* wihf = (const float*)d_in[4];
    const float* whhf = (const float*)d_in[5];
    const float* bf_  = (const float*)d_in[6];
    const float* wihb = (const float*)d_in[7];
    const float* whhb = (const float*)d_in[8];
    const float* bb_  = (const float*)d_in[9];
    const float* wfc  = (const float*)d_in[10];
    const float* bfc  = (const float*)d_in[11];
    const float* tr   = (const float*)d_in[12];

    char* ws = (char*)d_ws;
    unsigned short* et   = (unsigned short*)(ws);                 //  16,777,216 B
    unsigned short* wbf  = (unsigned short*)(ws + 16777216);      //   1,064,960 B (wih f|b cat, then wfc @ elem 524288)
    unsigned char*  w8   = (unsigned char*)(ws + 17842176);      //     524,288 B (whh f|b fp8)
    unsigned short* gx   = (unsigned short*)(ws + 18366464);      // 134,217,728 B
    unsigned short* hcat = (unsigned short*)(ws + 152584192);     //  33,554,432 B
    float* sc            = (float*)(ws + 186138624);              //   4,194,304 B

    hipMemsetAsync(d_out, 0, sizeof(float), stream);
    k_cast_weights<<<2080, 256, 0, stream>>>(wihf, wihb, wfc, wbf);
    k_cast_fp8<<<1024, 256, 0, stream>>>(whhf, whhb, w8);
    k_gather<<<4096, 256, 0, stream>>>(x, emb, et);
    dim3 g2(256, 16);
    k_gx<<<g2, 256, 0, stream>>>(et, wbf, bf_, bb_, gx);
    k_lstm<<<64, 512, 0, stream>>>(w8, gx, hcat);
    k_scores<<<512, 256, 0, stream>>>(hcat, wbf + 524288, bfc, sc);
    k_crf<<<64, 1024, 0, stream>>>(sc, tags, mask, tr, (float*)d_out);
}

// Round 8
// 909.723 us; speedup vs baseline: 1.0574x; 1.0001x over previous
//
#include <hip/hip_runtime.h>

typedef __attribute__((ext_vector_type(8))) short short8;
typedef __attribute__((ext_vector_type(4))) float floatx4;
typedef __attribute__((ext_vector_type(8))) int int8v;

__device__ __forceinline__ float bf2f(unsigned short u) {
    union { unsigned int i; float f; } c; c.i = ((unsigned int)u) << 16; return c.f;
}
__device__ __forceinline__ unsigned short f2bf(float f) {
    union { float f; unsigned int i; } c; c.f = f;
    unsigned int u = c.i;
    return (unsigned short)((u + 0x7FFFu + ((u >> 16) & 1u)) >> 16);
}
__device__ __forceinline__ unsigned short f2bf_rz(float f) {
    union { float f; unsigned int i; } c; c.f = f;
    return (unsigned short)(c.i >> 16);
}
__device__ __forceinline__ float sigm(float x) {
    return __builtin_amdgcn_rcpf(1.f + __expf(-x));
}
__device__ __forceinline__ float tanh_(float x) {
    return 1.f - 2.f * __builtin_amdgcn_rcpf(1.f + __expf(2.f * x));
}

__device__ __forceinline__ void glds16(const void* g, void* l) {
    __builtin_amdgcn_global_load_lds((const __attribute__((address_space(1))) unsigned int*)g,
                                     (__attribute__((address_space(3))) unsigned int*)l, 16, 0, 0);
}

// ---------------- fused prep: gather | cast bf16 weights | cast fp8 whh ----------------
// grid 7200x256: [0,4096) gather, [4096,6176) cast_weights, [6176,7200) cast_fp8
__global__ void k_prep(const int* __restrict__ x, const float* __restrict__ emb,
                       unsigned short* __restrict__ et,
                       const float* __restrict__ wihf, const float* __restrict__ wihb,
                       const float* __restrict__ wfc, unsigned short* __restrict__ wbf,
                       const float* __restrict__ whhf, const float* __restrict__ whhb,
                       unsigned char* __restrict__ w8) {
    const int bid = blockIdx.x;
    if (bid < 4096) {
        int id = bid * 256 + threadIdx.x;          // 1,048,576 total
        int m = id >> 5, fi = (id & 31) << 3;
        int b = m & 63, t = m >> 6;
        int v = x[b * 512 + t];
        const float4* s = (const float4*)(emb + ((size_t)v << 8) + fi);
        float4 a = s[0], q = s[1];
        uint4 o;
        o.x = (unsigned)f2bf(a.x) | ((unsigned)f2bf(a.y) << 16);
        o.y = (unsigned)f2bf(a.z) | ((unsigned)f2bf(a.w) << 16);
        o.z = (unsigned)f2bf(q.x) | ((unsigned)f2bf(q.y) << 16);
        o.w = (unsigned)f2bf(q.z) | ((unsigned)f2bf(q.w) << 16);
        *(uint4*)(et + ((size_t)m << 8) + fi) = o;
    } else if (bid < 6176) {
        int i = (bid - 4096) * 256 + threadIdx.x;
        if (i >= 532480) return;
        float v;
        if (i < 262144) v = wihf[i];
        else if (i < 524288) v = wihb[i - 262144];
        else v = wfc[i - 524288];
        wbf[i] = f2bf(v);
    } else {
        int i = (bid - 6176) * 256 + threadIdx.x;   // 262144 threads, 2 elems each
        if (i >= 262144) return;
        int e = i * 2;
        float a = (e < 262144) ? whhf[e] : whhb[e - 262144];
        float b = (e + 1 < 262144) ? whhf[e + 1] : whhb[e + 1 - 262144];
        int p = __builtin_amdgcn_cvt_pk_fp8_f32(a, b, 0, false);
        *(unsigned short*)(w8 + e) = (unsigned short)(p & 0xffff);
    }
}

// ---------------- gx = e @ w_ih.T + b, both dirs (N=2048), output bf16 [d][t][b][1024] ----------------
__global__ __launch_bounds__(256, 2) void k_gx(const unsigned short* __restrict__ et,
                                               const unsigned short* __restrict__ wcat,
                                               const float* __restrict__ bfv, const float* __restrict__ bbv,
                                               unsigned short* __restrict__ gx) {
    __shared__ unsigned short As[4096];
    __shared__ unsigned short Bs[4096];
    const int tid = threadIdx.x;
    const int w = tid >> 6, l = tid & 63, quad = l >> 4, col = l & 15;
    const size_t m0 = (size_t)blockIdx.x * 128, n0 = (size_t)blockIdx.y * 128;
    floatx4 C[4][4];
    #pragma unroll
    for (int i = 0; i < 4; ++i)
        #pragma unroll
        for (int j = 0; j < 4; ++j) C[i][j] = (floatx4){0.f, 0.f, 0.f, 0.f};
    const int srow = tid >> 2, scol = (tid & 3) * 16;
    for (int it = 0; it < 8; ++it) {
        const char* ga = (const char*)et + (m0 + srow) * 512 + it * 64 + scol;
        const char* gb = (const char*)wcat + (n0 + srow) * 512 + it * 64 + scol;
        glds16(ga,             (char*)As + w * 1024);
        glds16(ga + 64 * 512,  (char*)As + 4096 + w * 1024);
        glds16(gb,             (char*)Bs + w * 1024);
        glds16(gb + 64 * 512,  (char*)Bs + 4096 + w * 1024);
        __syncthreads();
        short8 Af[4], Bf[4];
        #pragma unroll
        for (int i = 0; i < 4; ++i) {
            Af[i] = *(const short8*)(As + (((w & 1) * 64 + i * 16 + col) * 32 + quad * 8));
            Bf[i] = *(const short8*)(Bs + (((w >> 1) * 64 + i * 16 + col) * 32 + quad * 8));
        }
        #pragma unroll
        for (int i = 0; i < 4; ++i)
            #pragma unroll
            for (int j = 0; j < 4; ++j)
                C[i][j] = __builtin_amdgcn_mfma_f32_16x16x32_bf16(Af[i], Bf[j], C[i][j], 0, 0, 0);
        __syncthreads();
    }
    const int mw = (w & 1) * 64, nw = (w >> 1) * 64;
    #pragma unroll
    for (int j = 0; j < 4; ++j) {
        int n = (int)n0 + nw + j * 16 + col;
        float bias = (n < 1024) ? bfv[n] : bbv[n - 1024];
        size_t dbase = (size_t)(n >> 10) * 33554432 + (size_t)(n & 1023);
        #pragma unroll
        for (int i = 0; i < 4; ++i)
            #pragma unroll
            for (int r = 0; r < 4; ++r) {
                size_t m = m0 + mw + i * 16 + quad * 4 + r;
                gx[dbase + m * 1024] = f2bf(C[i][j][r] + bias);
            }
    }
}

// ---------------- LSTM recurrence: 64 wgs = 2 dirs x 32 batch-groups of 2; 512 thr (8 waves) ----
// Swapped-operand MFMA: A = h (fp8), B = W fragments. Batch lives in A-row BLOCKS of 8
// (rows 0-7 = b0, 8-15 = b1) so C batch = quad>>1 for ANY r => z[g] = nts ? C[g][1][0] : C[g][0][0]
// (4 cndmask total). Lane owns (b = l>>5, u = 32w + (l&31)). g-outer MFMA ordering exposes
// early-gate VALU under later-gate MFMAs. Explicit c0/c1 zero-init (R4 form, 373us @ 88 VGPR).
// ONE raw s_barrier per step, lgkm-only drain.
__global__ __launch_bounds__(512, 2) void k_lstm(const unsigned char* __restrict__ w8_all,
                                                 const unsigned short* __restrict__ gx_all,
                                                 unsigned short* __restrict__ hcat) {
    const int d = blockIdx.x >> 5, bg = blockIdx.x & 31;
    const int tid = threadIdx.x, w = tid >> 6, l = tid & 63, quad = l >> 4, col = l & 15;
    const unsigned char* W = w8_all + (size_t)d * 262144;
    const unsigned short* G = gx_all + (size_t)d * 33554432;
    __shared__ __align__(16) unsigned char hld[2][2][288]; // 1,152 B  h fp8 [buf][batch][unit]

    // B-fragments (W): Wb[g][nt][kt] holds W[256g + 32w + 16nt + col][kt*128 + quad*32 .. +31]
    int8v Wb[4][2][2];
    #pragma unroll
    for (int g = 0; g < 4; ++g)
        #pragma unroll
        for (int nt = 0; nt < 2; ++nt)
            #pragma unroll
            for (int kt = 0; kt < 2; ++kt)
                Wb[g][nt][kt] = *(const int8v*)(W + (size_t)(256 * g + 32 * w + 16 * nt + col) * 256
                                                + kt * 128 + quad * 32);
    for (int i = tid; i < 288; i += 512) ((unsigned int*)hld)[i] = 0;

    const int b = l >> 5, u = 32 * w + (l & 31);           // this lane's (batch, unit)
    const int bglob = 2 * bg + b;
    const int nts = quad & 1;                              // nt select for z extraction
    const int hsel = (l >> 3) & 1;                         // batch block for A-fragment rows
    float cst = 0.f;
    const long gstep = d ? -65536 : 65536;                 // shorts per t in gx
    const long hstep = d ? -32768 : 32768;                 // shorts per t in hcat
    const unsigned short* gp = G + ((size_t)((d ? 511 : 0) * 64 + bglob) * 1024 + u);
    unsigned short* hp = hcat + ((size_t)((d ? 511 : 0) * 64 + bglob) * 512 + d * 256 + u);
    unsigned short gq0 = gp[0], gq1 = gp[256], gq2 = gp[512], gq3 = gp[768];
    gp += gstep;
    __syncthreads();

    #pragma clang loop unroll(disable)
    for (int step = 0; step < 512; ++step) {
        const int cur = step & 1;
        // ---- MFMA phase: A = h (row blocks of 8 per batch), B = W; g-outer for early z ----
        int8v Af[2];
        #pragma unroll
        for (int kt = 0; kt < 2; ++kt)
            Af[kt] = *(const int8v*)(&hld[cur][hsel][kt * 128 + quad * 32]);
        float z[4];
        #pragma unroll
        for (int g = 0; g < 4; ++g) {
            floatx4 c0 = (floatx4){0.f, 0.f, 0.f, 0.f};
            floatx4 c1 = (floatx4){0.f, 0.f, 0.f, 0.f};
            #pragma unroll
            for (int kt = 0; kt < 2; ++kt) {
                c0 = __builtin_amdgcn_mfma_scale_f32_16x16x128_f8f6f4(
                    Af[kt], Wb[g][0][kt], c0, 0, 0, 0, 0x7f7f7f7f, 0, 0x7f7f7f7f);
                c1 = __builtin_amdgcn_mfma_scale_f32_16x16x128_f8f6f4(
                    Af[kt], Wb[g][1][kt], c1, 0, 0, 0, 0x7f7f7f7f, 0, 0x7f7f7f7f);
            }
            z[g] = nts ? c1[0] : c0[0];
        }
        // ---- gate phase: fully distributed, one (batch,unit) per lane ----
        float vi = z[0] + bf2f(gq0);
        float vf = z[1] + bf2f(gq1);
        float vg = z[2] + bf2f(gq2);
        float vo = z[3] + bf2f(gq3);
        // prefetch next step's gx (stays in flight across the raw barrier)
        gq0 = gp[0]; gq1 = gp[256]; gq2 = gp[512]; gq3 = gp[768];
        gp += gstep;
        float cc = sigm(vf) * cst + sigm(vi) * tanh_(vg);
        cst = cc;
        float hf = sigm(vo) * tanh_(cc);
        *hp = f2bf_rz(hf);
        hp += hstep;
        int pk = __builtin_amdgcn_cvt_pk_fp8_f32(hf, hf, 0, false);
        hld[cur ^ 1][b][u] = (unsigned char)(pk & 0xff);
        // ---- step boundary: LDS-only drain + raw barrier (no vmcnt drain) ----
        __builtin_amdgcn_sched_barrier(0);
        asm volatile("s_waitcnt lgkmcnt(0)");
        __builtin_amdgcn_sched_barrier(0);
        __builtin_amdgcn_s_barrier();
        __builtin_amdgcn_sched_barrier(0);
    }
}

// ---------------- scores = hcat @ w_fc.T + b_fc, fp32 [t][b][32] ----------------
__global__ __launch_bounds__(256, 4) void k_scores(const unsigned short* __restrict__ hcat,
                                                   const unsigned short* __restrict__ wfc,
                                                   const float* __restrict__ bfc,
                                                   float* __restrict__ sc) {
    const int tid = threadIdx.x, w = tid >> 6, l = tid & 63, quad = l >> 4, col = l & 15;
    const int m0 = blockIdx.x * 64 + w * 16;
    floatx4 C0 = (floatx4){0.f, 0.f, 0.f, 0.f}, C1 = C0;
    #pragma unroll
    for (int kt = 0; kt < 16; ++kt) {
        short8 A  = *(const short8*)(hcat + (size_t)(m0 + col) * 512 + kt * 32 + quad * 8);
        short8 B0 = *(const short8*)(wfc + (size_t)col * 512 + kt * 32 + quad * 8);
        short8 B1 = *(const short8*)(wfc + (size_t)(16 + col) * 512 + kt * 32 + quad * 8);
        C0 = __builtin_amdgcn_mfma_f32_16x16x32_bf16(A, B0, C0, 0, 0, 0);
        C1 = __builtin_amdgcn_mfma_f32_16x16x32_bf16(A, B1, C1, 0, 0, 0);
    }
    float b0 = bfc[col], b1 = bfc[16 + col];
    #pragma unroll
    for (int r = 0; r < 4; ++r) {
        int m = m0 + quad * 4 + r;
        sc[(size_t)m * 32 + col] = C0[r] + b0;
        sc[(size_t)m * 32 + 16 + col] = C1[r] + b1;
    }
}

// ---------------- CRF: true path score + forward algorithm, loss += total - true ----------------
// Double-buffered alpha: ONE barrier per t-step; sc/mask prefetched one step ahead.
__global__ __launch_bounds__(1024, 1) void k_crf(const float* __restrict__ sc, const int* __restrict__ tags,
                                                 const int* __restrict__ mask, const float* __restrict__ tr,
                                                 float* __restrict__ out) {
    __shared__ float Tm[32][33];
    __shared__ float al[2][32];
    __shared__ float trueb;
    const int b = blockIdx.x, tid = threadIdx.x;
    { int i = tid >> 5, j = tid & 31; Tm[i][j] = tr[tid]; }
    __syncthreads();
    if (tid < 64) {
        float acc = 0.f; int cnt = 0;
        for (int t = tid; t < 512; t += 64) cnt += mask[b * 512 + t];
        for (int t = tid + 1; t < 512; t += 64) {
            if (mask[b * 512 + t]) {
                int tg = tags[b * 512 + t], tp = tags[b * 512 + t - 1];
                acc += Tm[tp][tg] + sc[((size_t)t * 64 + b) * 32 + tg];
            }
        }
        #pragma unroll
        for (int m = 1; m < 64; m <<= 1) { acc += __shfl_xor(acc, m); cnt += __shfl_xor(cnt, m); }
        if (tid == 0) {
            int tg0 = tags[b * 512];
            float first = Tm[30][tg0] + sc[(size_t)b * 32 + tg0];
            int lt = tags[b * 512 + cnt - 1];
            trueb = first + acc + Tm[lt][31];
        }
    }
    if (tid < 32) al[0][tid] = Tm[30][tid] + sc[(size_t)b * 32 + tid];
    __syncthreads();
    const int j = tid >> 5, i = tid & 31;
    int cur = 0;
    float scn = sc[((size_t)64 + b) * 32 + j];
    int mkn = mask[b * 512 + 1];
    #pragma clang loop unroll(disable)
    for (int t = 1; t < 512; ++t) {
        float v = al[cur][i] + Tm[i][j];
        float mx = v;
        #pragma unroll
        for (int m = 1; m < 32; m <<= 1) mx = fmaxf(mx, __shfl_xor(mx, m));
        float e = __expf(v - mx);
        #pragma unroll
        for (int m = 1; m < 32; m <<= 1) e += __shfl_xor(e, m);
        float nv = mx + __logf(e) + scn;
        int mk = mkn;
        int tn = t < 511 ? t + 1 : 511;
        scn = sc[((size_t)tn * 64 + b) * 32 + j];
        mkn = mask[b * 512 + tn];
        if (i == 0) al[cur ^ 1][j] = mk ? nv : al[cur][j];
        __syncthreads();
        cur ^= 1;
    }
    if (tid < 32) {
        float v = al[cur][tid] + Tm[tid][31];
        float mx = v;
        #pragma unroll
        for (int m = 1; m < 32; m <<= 1) mx = fmaxf(mx, __shfl_xor(mx, m));
        float e = __expf(v - mx);
        #pragma unroll
        for (int m = 1; m < 32; m <<= 1) e += __shfl_xor(e, m);
        if (tid == 0) atomicAdd(out, mx + __logf(e) - trueb);
    }
}

extern "C" void kernel_launch(void* const* d_in, const int* in_sizes, int n_in,
                              void* d_out, int out_size, void* d_ws, size_t ws_size,
                              hipStream_t stream) {
    const int* x      = (const int*)d_in[0];
    const int* tags   = (const int*)d_in[1];
    const int* mask   = (const int*)d_in[2];
    const float* emb  = (const float*)d_in[3];
    const float* wihf = (const float*)d_in[4];
    const float* whhf = (const float*)d_in[5];
    const float* bf_  = (const float*)d_in[6];
    const float* wihb = (const float*)d_in[7];
    const float* whhb = (const float*)d_in[8];
    const float* bb_  = (const float*)d_in[9];
    const float* wfc  = (const float*)d_in[10];
    const float* bfc  = (const float*)d_in[11];
    const float* tr   = (const float*)d_in[12];

    char* ws = (char*)d_ws;
    unsigned short* et   = (unsigned short*)(ws);                 //  16,777,216 B
    unsigned short* wbf  = (unsigned short*)(ws + 16777216);      //   1,064,960 B (wih f|b cat, then wfc @ elem 524288)
    unsigned char*  w8   = (unsigned char*)(ws + 17842176);      //     524,288 B (whh f|b fp8)
    unsigned short* gx   = (unsigned short*)(ws + 18366464);      // 134,217,728 B
    unsigned short* hcat = (unsigned short*)(ws + 152584192);     //  33,554,432 B
    float* sc            = (float*)(ws + 186138624);              //   4,194,304 B

    hipMemsetAsync(d_out, 0, sizeof(float), stream);
    k_prep<<<7200, 256, 0, stream>>>(x, emb, et, wihf, wihb, wfc, wbf, whhf, whhb, w8);
    dim3 g2(256, 16);
    k_gx<<<g2, 256, 0, stream>>>(et, wbf, bf_, bb_, gx);
    k_lstm<<<64, 512, 0, stream>>>(w8, gx, hcat);
    k_scores<<<512, 256, 0, stream>>>(hcat, wbf + 524288, bfc, sc);
    k_crf<<<64, 1024, 0, stream>>>(sc, tags, mask, tr, (float*)d_out);
}

// Round 9
// 887.519 us; speedup vs baseline: 1.0838x; 1.0250x over previous
//
#include <hip/hip_runtime.h>

typedef __attribute__((ext_vector_type(8))) short short8;
typedef __attribute__((ext_vector_type(4))) float floatx4;
typedef __attribute__((ext_vector_type(8))) int int8v;

__device__ __forceinline__ float bf2f(unsigned short u) {
    union { unsigned int i; float f; } c; c.i = ((unsigned int)u) << 16; return c.f;
}
__device__ __forceinline__ float asf(unsigned int u) {
    union { unsigned int i; float f; } c; c.i = u; return c.f;
}
__device__ __forceinline__ unsigned short f2bf(float f) {
    union { float f; unsigned int i; } c; c.f = f;
    unsigned int u = c.i;
    return (unsigned short)((u + 0x7FFFu + ((u >> 16) & 1u)) >> 16);
}
__device__ __forceinline__ unsigned short f2bf_rz(float f) {
    union { float f; unsigned int i; } c; c.f = f;
    return (unsigned short)(c.i >> 16);
}
__device__ __forceinline__ float sigm(float x) {
    return __builtin_amdgcn_rcpf(1.f + __expf(-x));
}
__device__ __forceinline__ float tanh_(float x) {
    return 1.f - 2.f * __builtin_amdgcn_rcpf(1.f + __expf(2.f * x));
}

__device__ __forceinline__ void glds16(const void* g, void* l) {
    __builtin_amdgcn_global_load_lds((const __attribute__((address_space(1))) unsigned int*)g,
                                     (__attribute__((address_space(3))) unsigned int*)l, 16, 0, 0);
}

// ---------------- fused prep: gather | cast bf16 weights | cast fp8 whh ----------------
// grid 7200x256: [0,4096) gather, [4096,6176) cast_weights, [6176,7200) cast_fp8
// w_ih rows are PERMUTED on store: dest row 4u+g <- src row 256g+u, so k_gx's output
// column n means (unit n>>2, gate n&3) and gx becomes gate-interleaved with identity
// (fully coalesced) writes. wfc stays linear.
__global__ void k_prep(const int* __restrict__ x, const float* __restrict__ emb,
                       unsigned short* __restrict__ et,
                       const float* __restrict__ wihf, const float* __restrict__ wihb,
                       const float* __restrict__ wfc, unsigned short* __restrict__ wbf,
                       const float* __restrict__ whhf, const float* __restrict__ whhb,
                       unsigned char* __restrict__ w8) {
    const int bid = blockIdx.x;
    if (bid < 4096) {
        int id = bid * 256 + threadIdx.x;          // 1,048,576 total
        int m = id >> 5, fi = (id & 31) << 3;
        int b = m & 63, t = m >> 6;
        int v = x[b * 512 + t];
        const float4* s = (const float4*)(emb + ((size_t)v << 8) + fi);
        float4 a = s[0], q = s[1];
        uint4 o;
        o.x = (unsigned)f2bf(a.x) | ((unsigned)f2bf(a.y) << 16);
        o.y = (unsigned)f2bf(a.z) | ((unsigned)f2bf(a.w) << 16);
        o.z = (unsigned)f2bf(q.x) | ((unsigned)f2bf(q.y) << 16);
        o.w = (unsigned)f2bf(q.z) | ((unsigned)f2bf(q.w) << 16);
        *(uint4*)(et + ((size_t)m << 8) + fi) = o;
    } else if (bid < 6176) {
        int i = (bid - 4096) * 256 + threadIdx.x;
        if (i >= 532480) return;
        float v;
        if (i < 524288) {
            int r = (i >> 8) & 1023, c = i & 255;              // dest row (within dir), col
            int src = (256 * (r & 3) + (r >> 2)) * 256 + c;    // src row 256g+u
            v = (i < 262144) ? wihf[src] : wihb[src];
        } else {
            v = wfc[i - 524288];
        }
        wbf[i] = f2bf(v);
    } else {
        int i = (bid - 6176) * 256 + threadIdx.x;   // 262144 threads, 2 elems each
        if (i >= 262144) return;
        int e = i * 2;
        float a = (e < 262144) ? whhf[e] : whhb[e - 262144];
        float b = (e + 1 < 262144) ? whhf[e + 1] : whhb[e + 1 - 262144];
        int p = __builtin_amdgcn_cvt_pk_fp8_f32(a, b, 0, false);
        *(unsigned short*)(w8 + e) = (unsigned short)(p & 0xffff);
    }
}

// ---------------- gx = e @ w_ih.T + b, both dirs (N=2048) ----------------
// Weight rows pre-permuted: output elem n = (unit n>>2, gate n&3). Write index is the
// identity (coalesced, R1-level); only the bias index decodes the permutation.
__global__ __launch_bounds__(256, 2) void k_gx(const unsigned short* __restrict__ et,
                                               const unsigned short* __restrict__ wcat,
                                               const float* __restrict__ bfv, const float* __restrict__ bbv,
                                               unsigned short* __restrict__ gx) {
    __shared__ unsigned short As[4096];
    __shared__ unsigned short Bs[4096];
    const int tid = threadIdx.x;
    const int w = tid >> 6, l = tid & 63, quad = l >> 4, col = l & 15;
    const size_t m0 = (size_t)blockIdx.x * 128, n0 = (size_t)blockIdx.y * 128;
    floatx4 C[4][4];
    #pragma unroll
    for (int i = 0; i < 4; ++i)
        #pragma unroll
        for (int j = 0; j < 4; ++j) C[i][j] = (floatx4){0.f, 0.f, 0.f, 0.f};
    const int srow = tid >> 2, scol = (tid & 3) * 16;
    for (int it = 0; it < 8; ++it) {
        const char* ga = (const char*)et + (m0 + srow) * 512 + it * 64 + scol;
        const char* gb = (const char*)wcat + (n0 + srow) * 512 + it * 64 + scol;
        glds16(ga,             (char*)As + w * 1024);
        glds16(ga + 64 * 512,  (char*)As + 4096 + w * 1024);
        glds16(gb,             (char*)Bs + w * 1024);
        glds16(gb + 64 * 512,  (char*)Bs + 4096 + w * 1024);
        __syncthreads();
        short8 Af[4], Bf[4];
        #pragma unroll
        for (int i = 0; i < 4; ++i) {
            Af[i] = *(const short8*)(As + (((w & 1) * 64 + i * 16 + col) * 32 + quad * 8));
            Bf[i] = *(const short8*)(Bs + (((w >> 1) * 64 + i * 16 + col) * 32 + quad * 8));
        }
        #pragma unroll
        for (int i = 0; i < 4; ++i)
            #pragma unroll
            for (int j = 0; j < 4; ++j)
                C[i][j] = __builtin_amdgcn_mfma_f32_16x16x32_bf16(Af[i], Bf[j], C[i][j], 0, 0, 0);
        __syncthreads();
    }
    const int mw = (w & 1) * 64, nw = (w >> 1) * 64;
    #pragma unroll
    for (int j = 0; j < 4; ++j) {
        int n = (int)n0 + nw + j * 16 + col;
        int nl = n & 1023;
        int bidx = ((nl >> 2) & 255) + 256 * (nl & 3);         // decode (unit,gate) -> gate-major bias
        float bias = (n < 1024) ? bfv[bidx] : bbv[bidx];
        size_t dbase = (size_t)(n >> 10) * 33554432 + (size_t)nl;
        #pragma unroll
        for (int i = 0; i < 4; ++i)
            #pragma unroll
            for (int r = 0; r < 4; ++r) {
                size_t m = m0 + mw + i * 16 + quad * 4 + r;
                gx[dbase + m * 1024] = f2bf(C[i][j][r] + bias);
            }
    }
}

// ---------------- LSTM recurrence: 64 wgs = 2 dirs x 32 batch-groups of 2; 512 thr (8 waves) ----
// Swapped-operand MFMA: A = h (fp8), B = W fragments. Batch lives in A-row BLOCKS of 8
// (rows 0-7 = b0, 8-15 = b1) so C batch = quad>>1 for ANY r => z[g] = nts ? C[g][1][0] : C[g][0][0]
// (4 cndmask total). Lane owns (b = l>>5, u = 32w + (l&31)). g-outer MFMA ordering exposes
// early-gate VALU under later-gate MFMAs. gx is gate-interleaved: ONE dwordx2 gq load/step
// (R4 form: 88 VGPR, 373us — 4-scalar form costs +8 VGPR and +19us).
// ONE raw s_barrier per step, lgkm-only drain.
__global__ __launch_bounds__(512, 2) void k_lstm(const unsigned char* __restrict__ w8_all,
                                                 const unsigned short* __restrict__ gx_all,
                                                 unsigned short* __restrict__ hcat) {
    const int d = blockIdx.x >> 5, bg = blockIdx.x & 31;
    const int tid = threadIdx.x, w = tid >> 6, l = tid & 63, quad = l >> 4, col = l & 15;
    const unsigned char* W = w8_all + (size_t)d * 262144;
    const unsigned short* G = gx_all + (size_t)d * 33554432;
    __shared__ __align__(16) unsigned char hld[2][2][288]; // 1,152 B  h fp8 [buf][batch][unit]

    // B-fragments (W): Wb[g][nt][kt] holds W[256g + 32w + 16nt + col][kt*128 + quad*32 .. +31]
    int8v Wb[4][2][2];
    #pragma unroll
    for (int g = 0; g < 4; ++g)
        #pragma unroll
        for (int nt = 0; nt < 2; ++nt)
            #pragma unroll
            for (int kt = 0; kt < 2; ++kt)
                Wb[g][nt][kt] = *(const int8v*)(W + (size_t)(256 * g + 32 * w + 16 * nt + col) * 256
                                                + kt * 128 + quad * 32);
    for (int i = tid; i < 288; i += 512) ((unsigned int*)hld)[i] = 0;

    const int b = l >> 5, u = 32 * w + (l & 31);           // this lane's (batch, unit)
    const int bglob = 2 * bg + b;
    const int nts = quad & 1;                              // nt select for z extraction
    const int hsel = (l >> 3) & 1;                         // batch block for A-fragment rows
    float cst = 0.f;
    const long gstep = d ? -65536 : 65536;                 // shorts per t in gx
    const long hstep = d ? -32768 : 32768;                 // shorts per t in hcat
    const unsigned short* gp = G + ((size_t)((d ? 511 : 0) * 64 + bglob) * 1024 + u * 4);
    unsigned short* hp = hcat + ((size_t)((d ? 511 : 0) * 64 + bglob) * 512 + d * 256 + u);
    uint2 gq = *(const uint2*)gp;                          // gates i,f (x) g,o (y) for this unit
    gp += gstep;
    __syncthreads();

    #pragma clang loop unroll(disable)
    for (int step = 0; step < 512; ++step) {
        const int cur = step & 1;
        // ---- MFMA phase: A = h (row blocks of 8 per batch), B = W; g-outer for early z ----
        int8v Af[2];
        #pragma unroll
        for (int kt = 0; kt < 2; ++kt)
            Af[kt] = *(const int8v*)(&hld[cur][hsel][kt * 128 + quad * 32]);
        float z[4];
        #pragma unroll
        for (int g = 0; g < 4; ++g) {
            floatx4 c0 = (floatx4){0.f, 0.f, 0.f, 0.f};
            floatx4 c1 = (floatx4){0.f, 0.f, 0.f, 0.f};
            #pragma unroll
            for (int kt = 0; kt < 2; ++kt) {
                c0 = __builtin_amdgcn_mfma_scale_f32_16x16x128_f8f6f4(
                    Af[kt], Wb[g][0][kt], c0, 0, 0, 0, 0x7f7f7f7f, 0, 0x7f7f7f7f);
                c1 = __builtin_amdgcn_mfma_scale_f32_16x16x128_f8f6f4(
                    Af[kt], Wb[g][1][kt], c1, 0, 0, 0, 0x7f7f7f7f, 0, 0x7f7f7f7f);
            }
            z[g] = nts ? c1[0] : c0[0];
        }
        // ---- gate phase: fully distributed, one (batch,unit) per lane ----
        float vi = z[0] + asf(gq.x << 16);
        float vf = z[1] + asf(gq.x & 0xffff0000u);
        float vg = z[2] + asf(gq.y << 16);
        float vo = z[3] + asf(gq.y & 0xffff0000u);
        // prefetch next step's gx (stays in flight across the raw barrier)
        gq = *(const uint2*)gp;
        gp += gstep;
        float cc = sigm(vf) * cst + sigm(vi) * tanh_(vg);
        cst = cc;
        float hf = sigm(vo) * tanh_(cc);
        *hp = f2bf_rz(hf);
        hp += hstep;
        int pk = __builtin_amdgcn_cvt_pk_fp8_f32(hf, hf, 0, false);
        hld[cur ^ 1][b][u] = (unsigned char)(pk & 0xff);
        // ---- step boundary: LDS-only drain + raw barrier (no vmcnt drain) ----
        __builtin_amdgcn_sched_barrier(0);
        asm volatile("s_waitcnt lgkmcnt(0)");
        __builtin_amdgcn_sched_barrier(0);
        __builtin_amdgcn_s_barrier();
        __builtin_amdgcn_sched_barrier(0);
    }
}

// ---------------- scores = hcat @ w_fc.T + b_fc, fp32 [t][b][32] ----------------
__global__ __launch_bounds__(256, 4) void k_scores(const unsigned short* __restrict__ hcat,
                                                   const unsigned short* __restrict__ wfc,
                                                   const float* __restrict__ bfc,
                                                   float* __restrict__ sc) {
    const int tid = threadIdx.x, w = tid >> 6, l = tid & 63, quad = l >> 4, col = l & 15;
    const int m0 = blockIdx.x * 64 + w * 16;
    floatx4 C0 = (floatx4){0.f, 0.f, 0.f, 0.f}, C1 = C0;
    #pragma unroll
    for (int kt = 0; kt < 16; ++kt) {
        short8 A  = *(const short8*)(hcat + (size_t)(m0 + col) * 512 + kt * 32 + quad * 8);
        short8 B0 = *(const short8*)(wfc + (size_t)col * 512 + kt * 32 + quad * 8);
        short8 B1 = *(const short8*)(wfc + (size_t)(16 + col) * 512 + kt * 32 + quad * 8);
        C0 = __builtin_amdgcn_mfma_f32_16x16x32_bf16(A, B0, C0, 0, 0, 0);
        C1 = __builtin_amdgcn_mfma_f32_16x16x32_bf16(A, B1, C1, 0, 0, 0);
    }
    float b0 = bfc[col], b1 = bfc[16 + col];
    #pragma unroll
    for (int r = 0; r < 4; ++r) {
        int m = m0 + quad * 4 + r;
        sc[(size_t)m * 32 + col] = C0[r] + b0;
        sc[(size_t)m * 32 + 16 + col] = C1[r] + b1;
    }
}

// ---------------- CRF: true path score + forward algorithm, loss += total - true ----------------
// Double-buffered alpha: ONE barrier per t-step; sc/mask prefetched one step ahead.
__global__ __launch_bounds__(1024, 1) void k_crf(const float* __restrict__ sc, const int* __restrict__ tags,
                                                 const int* __restrict__ mask, const float* __restrict__ tr,
                                                 float* __restrict__ out) {
    __shared__ float Tm[32][33];
    __shared__ float al[2][32];
    __shared__ float trueb;
    const int b = blockIdx.x, tid = threadIdx.x;
    { int i = tid >> 5, j = tid & 31; Tm[i][j] = tr[tid]; }
    __syncthreads();
    if (tid < 64) {
        float acc = 0.f; int cnt = 0;
        for (int t = tid; t < 512; t += 64) cnt += mask[b * 512 + t];
        for (int t = tid + 1; t < 512; t += 64) {
            if (mask[b * 512 + t]) {
                int tg = tags[b * 512 + t], tp = tags[b * 512 + t - 1];
                acc += Tm[tp][tg] + sc[((size_t)t * 64 + b) * 32 + tg];
            }
        }
        #pragma unroll
        for (int m = 1; m < 64; m <<= 1) { acc += __shfl_xor(acc, m); cnt += __shfl_xor(cnt, m); }
        if (tid == 0) {
            int tg0 = tags[b * 512];
            float first = Tm[30][tg0] + sc[(size_t)b * 32 + tg0];
            int lt = tags[b * 512 + cnt - 1];
            trueb = first + acc + Tm[lt][31];
        }
    }
    if (tid < 32) al[0][tid] = Tm[30][tid] + sc[(size_t)b * 32 + tid];
    __syncthreads();
    const int j = tid >> 5, i = tid & 31;
    int cur = 0;
    float scn = sc[((size_t)64 + b) * 32 + j];
    int mkn = mask[b * 512 + 1];
    #pragma clang loop unroll(disable)
    for (int t = 1; t < 512; ++t) {
        float v = al[cur][i] + Tm[i][j];
        float mx = v;
        #pragma unroll
        for (int m = 1; m < 32; m <<= 1) mx = fmaxf(mx, __shfl_xor(mx, m));
        float e = __expf(v - mx);
        #pragma unroll
        for (int m = 1; m < 32; m <<= 1) e += __shfl_xor(e, m);
        float nv = mx + __logf(e) + scn;
        int mk = mkn;
        int tn = t < 511 ? t + 1 : 511;
        scn = sc[((size_t)tn * 64 + b) * 32 + j];
        mkn = mask[b * 512 + tn];
        if (i == 0) al[cur ^ 1][j] = mk ? nv : al[cur][j];
        __syncthreads();
        cur ^= 1;
    }
    if (tid < 32) {
        float v = al[cur][tid] + Tm[tid][31];
        float mx = v;
        #pragma unroll
        for (int m = 1; m < 32; m <<= 1) mx = fmaxf(mx, __shfl_xor(mx, m));
        float e = __expf(v - mx);
        #pragma unroll
        for (int m = 1; m < 32; m <<= 1) e += __shfl_xor(e, m);
        if (tid == 0) atomicAdd(out, mx + __logf(e) - trueb);
    }
}

extern "C" void kernel_launch(void* const* d_in, const int* in_sizes, int n_in,
                              void* d_out, int out_size, void* d_ws, size_t ws_size,
                              hipStream_t stream) {
    const int* x      = (const int*)d_in[0];
    const int* tags   = (const int*)d_in[1];
    const int* mask   = (const int*)d_in[2];
    const float* emb  = (const float*)d_in[3];
    const float* wihf = (const float*)d_in[4];
    const float* whhf = (const float*)d_in[5];
    const float* bf_  = (const float*)d_in[6];
    const float* wihb = (const float*)d_in[7];
    const float* whhb = (const float*)d_in[8];
    const float* bb_  = (const float*)d_in[9];
    const float* wfc  = (const float*)d_in[10];
    const float* bfc  = (const float*)d_in[11];
    const float* tr   = (const float*)d_in[12];

    char* ws = (char*)d_ws;
    unsigned short* et   = (unsigned short*)(ws);                 //  16,777,216 B
    unsigned short* wbf  = (unsigned short*)(ws + 16777216);      //   1,064,960 B (wih f|b cat, then wfc @ elem 524288)
    unsigned char*  w8   = (unsigned char*)(ws + 17842176);      //     524,288 B (whh f|b fp8)
    unsigned short* gx   = (unsigned short*)(ws + 18366464);      // 134,217,728 B
    unsigned short* hcat = (unsigned short*)(ws + 152584192);     //  33,554,432 B
    float* sc            = (float*)(ws + 186138624);              //   4,194,304 B

    hipMemsetAsync(d_out, 0, sizeof(float), stream);
    k_prep<<<7200, 256, 0, stream>>>(x, emb, et, wihf, wihb, wfc, wbf, whhf, whhb, w8);
    dim3 g2(256, 16);
    k_gx<<<g2, 256, 0, stream>>>(et, wbf, bf_, bb_, gx);
    k_lstm<<<64, 512, 0, stream>>>(w8, gx, hcat);
    k_scores<<<512, 256, 0, stream>>>(hcat, wbf + 524288, bfc, sc);
    k_crf<<<64, 1024, 0, stream>>>(sc, tags, mask, tr, (float*)d_out);
}

// Round 10
// 883.334 us; speedup vs baseline: 1.0890x; 1.0047x over previous
//
#include <hip/hip_runtime.h>

typedef __attribute__((ext_vector_type(8))) short short8;
typedef __attribute__((ext_vector_type(4))) float floatx4;
typedef __attribute__((ext_vector_type(8))) int int8v;

__device__ __forceinline__ float bf2f(unsigned short u) {
    union { unsigned int i; float f; } c; c.i = ((unsigned int)u) << 16; return c.f;
}
__device__ __forceinline__ float asf(unsigned int u) {
    union { unsigned int i; float f; } c; c.i = u; return c.f;
}
__device__ __forceinline__ unsigned short f2bf(float f) {
    union { float f; unsigned int i; } c; c.f = f;
    unsigned int u = c.i;
    return (unsigned short)((u + 0x7FFFu + ((u >> 16) & 1u)) >> 16);
}
__device__ __forceinline__ unsigned short f2bf_rz(float f) {
    union { float f; unsigned int i; } c; c.f = f;
    return (unsigned short)(c.i >> 16);
}
__device__ __forceinline__ float sigm(float x) {
    return __builtin_amdgcn_rcpf(1.f + __expf(-x));
}
__device__ __forceinline__ float tanh_(float x) {
    return 1.f - 2.f * __builtin_amdgcn_rcpf(1.f + __expf(2.f * x));
}

__device__ __forceinline__ void glds16(const void* g, void* l) {
    __builtin_amdgcn_global_load_lds((const __attribute__((address_space(1))) unsigned int*)g,
                                     (__attribute__((address_space(3))) unsigned int*)l, 16, 0, 0);
}

// ---------------- fused prep: gather | cast bf16 weights | cast fp8 whh ----------------
// grid 7200x256: [0,4096) gather, [4096,6176) cast_weights, [6176,7200) cast_fp8
// w_ih rows are PERMUTED on store: dest row 4u+g <- src row 256g+u, so k_gx's output
// column n means (unit n>>2, gate n&3) and gx becomes gate-interleaved with identity
// (fully coalesced) writes. wfc stays linear.
__global__ void k_prep(const int* __restrict__ x, const float* __restrict__ emb,
                       unsigned short* __restrict__ et,
                       const float* __restrict__ wihf, const float* __restrict__ wihb,
                       const float* __restrict__ wfc, unsigned short* __restrict__ wbf,
                       const float* __restrict__ whhf, const float* __restrict__ whhb,
                       unsigned char* __restrict__ w8) {
    const int bid = blockIdx.x;
    if (bid < 4096) {
        int id = bid * 256 + threadIdx.x;          // 1,048,576 total
        int m = id >> 5, fi = (id & 31) << 3;
        int b = m & 63, t = m >> 6;
        int v = x[b * 512 + t];
        const float4* s = (const float4*)(emb + ((size_t)v << 8) + fi);
        float4 a = s[0], q = s[1];
        uint4 o;
        o.x = (unsigned)f2bf(a.x) | ((unsigned)f2bf(a.y) << 16);
        o.y = (unsigned)f2bf(a.z) | ((unsigned)f2bf(a.w) << 16);
        o.z = (unsigned)f2bf(q.x) | ((unsigned)f2bf(q.y) << 16);
        o.w = (unsigned)f2bf(q.z) | ((unsigned)f2bf(q.w) << 16);
        *(uint4*)(et + ((size_t)m << 8) + fi) = o;
    } else if (bid < 6176) {
        int i = (bid - 4096) * 256 + threadIdx.x;
        if (i >= 532480) return;
        float v;
        if (i < 524288) {
            int r = (i >> 8) & 1023, c = i & 255;              // dest row (within dir), col
            int src = (256 * (r & 3) + (r >> 2)) * 256 + c;    // src row 256g+u
            v = (i < 262144) ? wihf[src] : wihb[src];
        } else {
            v = wfc[i - 524288];
        }
        wbf[i] = f2bf(v);
    } else {
        int i = (bid - 6176) * 256 + threadIdx.x;   // 262144 threads, 2 elems each
        if (i >= 262144) return;
        int e = i * 2;
        float a = (e < 262144) ? whhf[e] : whhb[e - 262144];
        float b = (e + 1 < 262144) ? whhf[e + 1] : whhb[e + 1 - 262144];
        int p = __builtin_amdgcn_cvt_pk_fp8_f32(a, b, 0, false);
        *(unsigned short*)(w8 + e) = (unsigned short)(p & 0xffff);
    }
}

// ---------------- gx = e @ w_ih.T + b, both dirs (N=2048) ----------------
// Weight rows pre-permuted: output elem n = (unit n>>2, gate n&3).
// Epilogue stages the 128x128 C-tile in LDS (stride-136 rows) then copies with
// 256-B-per-row coalesced stores (old path: 32-B granule scatter, 4 segments/instr).
__global__ __launch_bounds__(256, 2) void k_gx(const unsigned short* __restrict__ et,
                                               const unsigned short* __restrict__ wcat,
                                               const float* __restrict__ bfv, const float* __restrict__ bbv,
                                               unsigned short* __restrict__ gx) {
    __shared__ unsigned short S[17408];            // 34,816 B: As/Bs during K-loop, C-tile after
    unsigned short* As = S;
    unsigned short* Bs = S + 4096;
    const int tid = threadIdx.x;
    const int w = tid >> 6, l = tid & 63, quad = l >> 4, col = l & 15;
    const size_t m0 = (size_t)blockIdx.x * 128, n0 = (size_t)blockIdx.y * 128;
    floatx4 C[4][4];
    #pragma unroll
    for (int i = 0; i < 4; ++i)
        #pragma unroll
        for (int j = 0; j < 4; ++j) C[i][j] = (floatx4){0.f, 0.f, 0.f, 0.f};
    const int srow = tid >> 2, scol = (tid & 3) * 16;
    for (int it = 0; it < 8; ++it) {
        const char* ga = (const char*)et + (m0 + srow) * 512 + it * 64 + scol;
        const char* gb = (const char*)wcat + (n0 + srow) * 512 + it * 64 + scol;
        glds16(ga,             (char*)As + w * 1024);
        glds16(ga + 64 * 512,  (char*)As + 4096 + w * 1024);
        glds16(gb,             (char*)Bs + w * 1024);
        glds16(gb + 64 * 512,  (char*)Bs + 4096 + w * 1024);
        __syncthreads();
        short8 Af[4], Bf[4];
        #pragma unroll
        for (int i = 0; i < 4; ++i) {
            Af[i] = *(const short8*)(As + (((w & 1) * 64 + i * 16 + col) * 32 + quad * 8));
            Bf[i] = *(const short8*)(Bs + (((w >> 1) * 64 + i * 16 + col) * 32 + quad * 8));
        }
        #pragma unroll
        for (int i = 0; i < 4; ++i)
            #pragma unroll
            for (int j = 0; j < 4; ++j)
                C[i][j] = __builtin_amdgcn_mfma_f32_16x16x32_bf16(Af[i], Bf[j], C[i][j], 0, 0, 0);
        __syncthreads();
    }
    // ---- stage C + bias into LDS tile [128][136] ----
    const int mw = (w & 1) * 64, nw = (w >> 1) * 64;
    #pragma unroll
    for (int j = 0; j < 4; ++j) {
        int nl_ = nw + j * 16 + col;                           // local n 0..127
        int n = (int)n0 + nl_;
        int nl = n & 1023;
        int bidx = ((nl >> 2) & 255) + 256 * (nl & 3);         // decode (unit,gate) -> gate-major bias
        float bias = (n < 1024) ? bfv[bidx] : bbv[bidx];
        #pragma unroll
        for (int i = 0; i < 4; ++i)
            #pragma unroll
            for (int r = 0; r < 4; ++r) {
                int ml = mw + i * 16 + quad * 4 + r;           // local m 0..127
                S[ml * 136 + nl_] = f2bf(C[i][j][r] + bias);
            }
    }
    __syncthreads();
    // ---- coalesced copy out: 16 lanes cover one 256-B row; wave = 4 contiguous rows ----
    const int row_ = tid >> 4, seg = (tid & 15) * 8;
    const size_t gbase = (size_t)(n0 >> 10) * 33554432 + (size_t)(n0 & 1023);
    #pragma unroll
    for (int k = 0; k < 8; ++k) {
        int ml = k * 16 + row_;
        *(short8*)(gx + gbase + (m0 + ml) * 1024 + seg) = *(const short8*)(&S[ml * 136 + seg]);
    }
}

// ---------------- LSTM recurrence: 64 wgs = 2 dirs x 32 batch-groups of 2; 512 thr (8 waves) ----
// Swapped-operand MFMA: A = h (fp8), B = W fragments. Batch lives in A-row BLOCKS of 8
// (rows 0-7 = b0, 8-15 = b1) so C batch = quad>>1 for ANY r => z[g] = nts ? C[g][1][0] : C[g][0][0]
// (4 cndmask total). Lane owns (b = l>>5, u = 32w + (l&31)). g-outer MFMA ordering exposes
// early-gate VALU under later-gate MFMAs. gx is gate-interleaved: ONE dwordx2 gq load/step
// (R4 form: 88 VGPR, 373-376us — 4-scalar form costs +8 VGPR and +17us).
// ONE raw s_barrier per step, lgkm-only drain.
__global__ __launch_bounds__(512, 2) void k_lstm(const unsigned char* __restrict__ w8_all,
                                                 const unsigned short* __restrict__ gx_all,
                                                 unsigned short* __restrict__ hcat) {
    const int d = blockIdx.x >> 5, bg = blockIdx.x & 31;
    const int tid = threadIdx.x, w = tid >> 6, l = tid & 63, quad = l >> 4, col = l & 15;
    const unsigned char* W = w8_all + (size_t)d * 262144;
    const unsigned short* G = gx_all + (size_t)d * 33554432;
    __shared__ __align__(16) unsigned char hld[2][2][288]; // 1,152 B  h fp8 [buf][batch][unit]

    // B-fragments (W): Wb[g][nt][kt] holds W[256g + 32w + 16nt + col][kt*128 + quad*32 .. +31]
    int8v Wb[4][2][2];
    #pragma unroll
    for (int g = 0; g < 4; ++g)
        #pragma unroll
        for (int nt = 0; nt < 2; ++nt)
            #pragma unroll
            for (int kt = 0; kt < 2; ++kt)
                Wb[g][nt][kt] = *(const int8v*)(W + (size_t)(256 * g + 32 * w + 16 * nt + col) * 256
                                                + kt * 128 + quad * 32);
    for (int i = tid; i < 288; i += 512) ((unsigned int*)hld)[i] = 0;

    const int b = l >> 5, u = 32 * w + (l & 31);           // this lane's (batch, unit)
    const int bglob = 2 * bg + b;
    const int nts = quad & 1;                              // nt select for z extraction
    const int hsel = (l >> 3) & 1;                         // batch block for A-fragment rows
    float cst = 0.f;
    const long gstep = d ? -65536 : 65536;                 // shorts per t in gx
    const long hstep = d ? -32768 : 32768;                 // shorts per t in hcat
    const unsigned short* gp = G + ((size_t)((d ? 511 : 0) * 64 + bglob) * 1024 + u * 4);
    unsigned short* hp = hcat + ((size_t)((d ? 511 : 0) * 64 + bglob) * 512 + d * 256 + u);
    uint2 gq = *(const uint2*)gp;                          // gates i,f (x) g,o (y) for this unit
    gp += gstep;
    __syncthreads();

    #pragma clang loop unroll(disable)
    for (int step = 0; step < 512; ++step) {
        const int cur = step & 1;
        // ---- MFMA phase: A = h (row blocks of 8 per batch), B = W; g-outer for early z ----
        int8v Af[2];
        #pragma unroll
        for (int kt = 0; kt < 2; ++kt)
            Af[kt] = *(const int8v*)(&hld[cur][hsel][kt * 128 + quad * 32]);
        float z[4];
        #pragma unroll
        for (int g = 0; g < 4; ++g) {
            floatx4 c0 = (floatx4){0.f, 0.f, 0.f, 0.f};
            floatx4 c1 = (floatx4){0.f, 0.f, 0.f, 0.f};
            #pragma unroll
            for (int kt = 0; kt < 2; ++kt) {
                c0 = __builtin_amdgcn_mfma_scale_f32_16x16x128_f8f6f4(
                    Af[kt], Wb[g][0][kt], c0, 0, 0, 0, 0x7f7f7f7f, 0, 0x7f7f7f7f);
                c1 = __builtin_amdgcn_mfma_scale_f32_16x16x128_f8f6f4(
                    Af[kt], Wb[g][1][kt], c1, 0, 0, 0, 0x7f7f7f7f, 0, 0x7f7f7f7f);
            }
            z[g] = nts ? c1[0] : c0[0];
        }
        // ---- gate phase: fully distributed, one (batch,unit) per lane ----
        float vi = z[0] + asf(gq.x << 16);
        float vf = z[1] + asf(gq.x & 0xffff0000u);
        float vg = z[2] + asf(gq.y << 16);
        float vo = z[3] + asf(gq.y & 0xffff0000u);
        // prefetch next step's gx (stays in flight across the raw barrier)
        gq = *(const uint2*)gp;
        gp += gstep;
        float cc = sigm(vf) * cst + sigm(vi) * tanh_(vg);
        cst = cc;
        float hf = sigm(vo) * tanh_(cc);
        *hp = f2bf_rz(hf);
        hp += hstep;
        int pk = __builtin_amdgcn_cvt_pk_fp8_f32(hf, hf, 0, false);
        hld[cur ^ 1][b][u] = (unsigned char)(pk & 0xff);
        // ---- step boundary: LDS-only drain + raw barrier (no vmcnt drain) ----
        __builtin_amdgcn_sched_barrier(0);
        asm volatile("s_waitcnt lgkmcnt(0)");
        __builtin_amdgcn_sched_barrier(0);
        __builtin_amdgcn_s_barrier();
        __builtin_amdgcn_sched_barrier(0);
    }
}

// ---------------- scores = hcat @ w_fc.T + b_fc, fp32 [t][b][32] ----------------
__global__ __launch_bounds__(256, 4) void k_scores(const unsigned short* __restrict__ hcat,
                                                   const unsigned short* __restrict__ wfc,
                                                   const float* __restrict__ bfc,
                                                   float* __restrict__ sc) {
    const int tid = threadIdx.x, w = tid >> 6, l = tid & 63, quad = l >> 4, col = l & 15;
    const int m0 = blockIdx.x * 64 + w * 16;
    floatx4 C0 = (floatx4){0.f, 0.f, 0.f, 0.f}, C1 = C0;
    #pragma unroll
    for (int kt = 0; kt < 16; ++kt) {
        short8 A  = *(const short8*)(hcat + (size_t)(m0 + col) * 512 + kt * 32 + quad * 8);
        short8 B0 = *(const short8*)(wfc + (size_t)col * 512 + kt * 32 + quad * 8);
        short8 B1 = *(const short8*)(wfc + (size_t)(16 + col) * 512 + kt * 32 + quad * 8);
        C0 = __builtin_amdgcn_mfma_f32_16x16x32_bf16(A, B0, C0, 0, 0, 0);
        C1 = __builtin_amdgcn_mfma_f32_16x16x32_bf16(A, B1, C1, 0, 0, 0);
    }
    float b0 = bfc[col], b1 = bfc[16 + col];
    #pragma unroll
    for (int r = 0; r < 4; ++r) {
        int m = m0 + quad * 4 + r;
        sc[(size_t)m * 32 + col] = C0[r] + b0;
        sc[(size_t)m * 32 + 16 + col] = C1[r] + b1;
    }
}

// ---------------- CRF: true path score + forward algorithm, loss += total - true ----------------
// Double-buffered alpha: ONE barrier per t-step; sc/mask prefetched one step ahead.
__global__ __launch_bounds__(1024, 1) void k_crf(const float* __restrict__ sc, const int* __restrict__ tags,
                                                 const int* __restrict__ mask, const float* __restrict__ tr,
                                                 float* __restrict__ out) {
    __shared__ float Tm[32][33];
    __shared__ float al[2][32];
    __shared__ float trueb;
    const int b = blockIdx.x, tid = threadIdx.x;
    { int i = tid >> 5, j = tid & 31; Tm[i][j] = tr[tid]; }
    __syncthreads();
    if (tid < 64) {
        float acc = 0.f; int cnt = 0;
        for (int t = tid; t < 512; t += 64) cnt += mask[b * 512 + t];
        for (int t = tid + 1; t < 512; t += 64) {
            if (mask[b * 512 + t]) {
                int tg = tags[b * 512 + t], tp = tags[b * 512 + t - 1];
                acc += Tm[tp][tg] + sc[((size_t)t * 64 + b) * 32 + tg];
            }
        }
        #pragma unroll
        for (int m = 1; m < 64; m <<= 1) { acc += __shfl_xor(acc, m); cnt += __shfl_xor(cnt, m); }
        if (tid == 0) {
            int tg0 = tags[b * 512];
            float first = Tm[30][tg0] + sc[(size_t)b * 32 + tg0];
            int lt = tags[b * 512 + cnt - 1];
            trueb = first + acc + Tm[lt][31];
        }
    }
    if (tid < 32) al[0][tid] = Tm[30][tid] + sc[(size_t)b * 32 + tid];
    __syncthreads();
    const int j = tid >> 5, i = tid & 31;
    int cur = 0;
    float scn = sc[((size_t)64 + b) * 32 + j];
    int mkn = mask[b * 512 + 1];
    #pragma clang loop unroll(disable)
    for (int t = 1; t < 512; ++t) {
        float v = al[cur][i] + Tm[i][j];
        float mx = v;
        #pragma unroll
        for (int m = 1; m < 32; m <<= 1) mx = fmaxf(mx, __shfl_xor(mx, m));
        float e = __expf(v - mx);
        #pragma unroll
        for (int m = 1; m < 32; m <<= 1) e += __shfl_xor(e, m);
        float nv = mx + __logf(e) + scn;
        int mk = mkn;
        int tn = t < 511 ? t + 1 : 511;
        scn = sc[((size_t)tn * 64 + b) * 32 + j];
        mkn = mask[b * 512 + tn];
        if (i == 0) al[cur ^ 1][j] = mk ? nv : al[cur][j];
        __syncthreads();
        cur ^= 1;
    }
    if (tid < 32) {
        float v = al[cur][tid] + Tm[tid][31];
        float mx = v;
        #pragma unroll
        for (int m = 1; m < 32; m <<= 1) mx = fmaxf(mx, __shfl_xor(mx, m));
        float e = __expf(v - mx);
        #pragma unroll
        for (int m = 1; m < 32; m <<= 1) e += __shfl_xor(e, m);
        if (tid == 0) atomicAdd(out, mx + __logf(e) - trueb);
    }
}

extern "C" void kernel_launch(void* const* d_in, const int* in_sizes, int n_in,
                              void* d_out, int out_size, void* d_ws, size_t ws_size,
                              hipStream_t stream) {
    const int* x      = (const int*)d_in[0];
    const int* tags   = (const int*)d_in[1];
    const int* mask   = (const int*)d_in[2];
    const float* emb  = (const float*)d_in[3];
    const float* wihf = (const float*)d_in[4];
    const float* whhf = (const float*)d_in[5];
    const float* bf_  = (const float*)d_in[6];
    const float* wihb = (const float*)d_in[7];
    const float* whhb = (const float*)d_in[8];
    const float* bb_  = (const float*)d_in[9];
    const float* wfc  = (const float*)d_in[10];
    const float* bfc  = (const float*)d_in[11];
    const float* tr   = (const float*)d_in[12];

    char* ws = (char*)d_ws;
    unsigned short* et   = (unsigned short*)(ws);                 //  16,777,216 B
    unsigned short* wbf  = (unsigned short*)(ws + 16777216);      //   1,064,960 B (wih f|b cat, then wfc @ elem 524288)
    unsigned char*  w8   = (unsigned char*)(ws + 17842176);      //     524,288 B (whh f|b fp8)
    unsigned short* gx   = (unsigned short*)(ws + 18366464);      // 134,217,728 B
    unsigned short* hcat = (unsigned short*)(ws + 152584192);     //  33,554,432 B
    float* sc            = (float*)(ws + 186138624);              //   4,194,304 B

    hipMemsetAsync(d_out, 0, sizeof(float), stream);
    k_prep<<<7200, 256, 0, stream>>>(x, emb, et, wihf, wihb, wfc, wbf, whhf, whhb, w8);
    dim3 g2(256, 16);
    k_gx<<<g2, 256, 0, stream>>>(et, wbf, bf_, bb_, gx);
    k_lstm<<<64, 512, 0, stream>>>(w8, gx, hcat);
    k_scores<<<512, 256, 0, stream>>>(hcat, wbf + 524288, bfc, sc);
    k_crf<<<64, 1024, 0, stream>>>(sc, tags, mask, tr, (float*)d_out);
}

// Round 11
// 853.499 us; speedup vs baseline: 1.1270x; 1.0350x over previous
//
#include <hip/hip_runtime.h>

typedef __attribute__((ext_vector_type(8))) short short8;
typedef __attribute__((ext_vector_type(4))) float floatx4;
typedef __attribute__((ext_vector_type(8))) int int8v;

__device__ __forceinline__ float bf2f(unsigned short u) {
    union { unsigned int i; float f; } c; c.i = ((unsigned int)u) << 16; return c.f;
}
__device__ __forceinline__ float asf(unsigned int u) {
    union { unsigned int i; float f; } c; c.i = u; return c.f;
}
__device__ __forceinline__ unsigned short f2bf(float f) {
    union { float f; unsigned int i; } c; c.f = f;
    unsigned int u = c.i;
    return (unsigned short)((u + 0x7FFFu + ((u >> 16) & 1u)) >> 16);
}
__device__ __forceinline__ unsigned short f2bf_rz(float f) {
    union { float f; unsigned int i; } c; c.f = f;
    return (unsigned short)(c.i >> 16);
}
__device__ __forceinline__ float sigm(float x) {
    return __builtin_amdgcn_rcpf(1.f + __expf(-x));
}
__device__ __forceinline__ float tanh_(float x) {
    return 1.f - 2.f * __builtin_amdgcn_rcpf(1.f + __expf(2.f * x));
}

__device__ __forceinline__ void glds16(const void* g, void* l) {
    __builtin_amdgcn_global_load_lds((const __attribute__((address_space(1))) unsigned int*)g,
                                     (__attribute__((address_space(3))) unsigned int*)l, 16, 0, 0);
}

// ---------------- fused prep: gather | cast bf16 weights | cast fp8 whh ----------------
// grid 7200x256: [0,4096) gather, [4096,6176) cast_weights, [6176,7200) cast_fp8
// w_ih rows are PERMUTED on store: dest row 4u+g <- src row 256g+u, so k_gx's output
// column n means (unit n>>2, gate n&3) and gx becomes gate-interleaved with identity
// (fully coalesced) writes. wfc stays linear.
__global__ void k_prep(const int* __restrict__ x, const float* __restrict__ emb,
                       unsigned short* __restrict__ et,
                       const float* __restrict__ wihf, const float* __restrict__ wihb,
                       const float* __restrict__ wfc, unsigned short* __restrict__ wbf,
                       const float* __restrict__ whhf, const float* __restrict__ whhb,
                       unsigned char* __restrict__ w8) {
    const int bid = blockIdx.x;
    if (bid < 4096) {
        int id = bid * 256 + threadIdx.x;          // 1,048,576 total
        int m = id >> 5, fi = (id & 31) << 3;
        int b = m & 63, t = m >> 6;
        int v = x[b * 512 + t];
        const float4* s = (const float4*)(emb + ((size_t)v << 8) + fi);
        float4 a = s[0], q = s[1];
        uint4 o;
        o.x = (unsigned)f2bf(a.x) | ((unsigned)f2bf(a.y) << 16);
        o.y = (unsigned)f2bf(a.z) | ((unsigned)f2bf(a.w) << 16);
        o.z = (unsigned)f2bf(q.x) | ((unsigned)f2bf(q.y) << 16);
        o.w = (unsigned)f2bf(q.z) | ((unsigned)f2bf(q.w) << 16);
        *(uint4*)(et + ((size_t)m << 8) + fi) = o;
    } else if (bid < 6176) {
        int i = (bid - 4096) * 256 + threadIdx.x;
        if (i >= 532480) return;
        float v;
        if (i < 524288) {
            int r = (i >> 8) & 1023, c = i & 255;              // dest row (within dir), col
            int src = (256 * (r & 3) + (r >> 2)) * 256 + c;    // src row 256g+u
            v = (i < 262144) ? wihf[src] : wihb[src];
        } else {
            v = wfc[i - 524288];
        }
        wbf[i] = f2bf(v);
    } else {
        int i = (bid - 6176) * 256 + threadIdx.x;   // 262144 threads, 2 elems each
        if (i >= 262144) return;
        int e = i * 2;
        float a = (e < 262144) ? whhf[e] : whhb[e - 262144];
        float b = (e + 1 < 262144) ? whhf[e + 1] : whhb[e + 1 - 262144];
        int p = __builtin_amdgcn_cvt_pk_fp8_f32(a, b, 0, false);
        *(unsigned short*)(w8 + e) = (unsigned short)(p & 0xffff);
    }
}

// ---------------- gx = e @ w_ih.T + b, both dirs (N=2048) ----------------
// Weight rows pre-permuted: output elem n = (unit n>>2, gate n&3).
// Epilogue stages the 128x128 C-tile in LDS (stride-136 rows) then copies with
// 256-B-per-row coalesced stores.
__global__ __launch_bounds__(256, 2) void k_gx(const unsigned short* __restrict__ et,
                                               const unsigned short* __restrict__ wcat,
                                               const float* __restrict__ bfv, const float* __restrict__ bbv,
                                               unsigned short* __restrict__ gx) {
    __shared__ unsigned short S[17408];            // 34,816 B: As/Bs during K-loop, C-tile after
    unsigned short* As = S;
    unsigned short* Bs = S + 4096;
    const int tid = threadIdx.x;
    const int w = tid >> 6, l = tid & 63, quad = l >> 4, col = l & 15;
    const size_t m0 = (size_t)blockIdx.x * 128, n0 = (size_t)blockIdx.y * 128;
    floatx4 C[4][4];
    #pragma unroll
    for (int i = 0; i < 4; ++i)
        #pragma unroll
        for (int j = 0; j < 4; ++j) C[i][j] = (floatx4){0.f, 0.f, 0.f, 0.f};
    const int srow = tid >> 2, scol = (tid & 3) * 16;
    for (int it = 0; it < 8; ++it) {
        const char* ga = (const char*)et + (m0 + srow) * 512 + it * 64 + scol;
        const char* gb = (const char*)wcat + (n0 + srow) * 512 + it * 64 + scol;
        glds16(ga,             (char*)As + w * 1024);
        glds16(ga + 64 * 512,  (char*)As + 4096 + w * 1024);
        glds16(gb,             (char*)Bs + w * 1024);
        glds16(gb + 64 * 512,  (char*)Bs + 4096 + w * 1024);
        __syncthreads();
        short8 Af[4], Bf[4];
        #pragma unroll
        for (int i = 0; i < 4; ++i) {
            Af[i] = *(const short8*)(As + (((w & 1) * 64 + i * 16 + col) * 32 + quad * 8));
            Bf[i] = *(const short8*)(Bs + (((w >> 1) * 64 + i * 16 + col) * 32 + quad * 8));
        }
        #pragma unroll
        for (int i = 0; i < 4; ++i)
            #pragma unroll
            for (int j = 0; j < 4; ++j)
                C[i][j] = __builtin_amdgcn_mfma_f32_16x16x32_bf16(Af[i], Bf[j], C[i][j], 0, 0, 0);
        __syncthreads();
    }
    // ---- stage C + bias into LDS tile [128][136] ----
    const int mw = (w & 1) * 64, nw = (w >> 1) * 64;
    #pragma unroll
    for (int j = 0; j < 4; ++j) {
        int nl_ = nw + j * 16 + col;                           // local n 0..127
        int n = (int)n0 + nl_;
        int nl = n & 1023;
        int bidx = ((nl >> 2) & 255) + 256 * (nl & 3);         // decode (unit,gate) -> gate-major bias
        float bias = (n < 1024) ? bfv[bidx] : bbv[bidx];
        #pragma unroll
        for (int i = 0; i < 4; ++i)
            #pragma unroll
            for (int r = 0; r < 4; ++r) {
                int ml = mw + i * 16 + quad * 4 + r;           // local m 0..127
                S[ml * 136 + nl_] = f2bf(C[i][j][r] + bias);
            }
    }
    __syncthreads();
    // ---- coalesced copy out: 16 lanes cover one 256-B row; wave = 4 contiguous rows ----
    const int row_ = tid >> 4, seg = (tid & 15) * 8;
    const size_t gbase = (size_t)(n0 >> 10) * 33554432 + (size_t)(n0 & 1023);
    #pragma unroll
    for (int k = 0; k < 8; ++k) {
        int ml = k * 16 + row_;
        *(short8*)(gx + gbase + (m0 + ml) * 1024 + seg) = *(const short8*)(&S[ml * 136 + seg]);
    }
}

// ---------------- LSTM recurrence: 64 wgs = 2 dirs x 32 batch-groups of 2; 512 thr (8 waves) ----
// Swapped-operand MFMA: A = h (fp8), B = W fragments. Batch lives in A-row BLOCKS of 8
// (rows 0-7 = b0, 8-15 = b1) so C batch = quad>>1 for ANY r => z[g] = nts ? C[g][1][0] : C[g][0][0]
// (4 cndmask total). Lane owns (b = l>>5, u = 32w + (l&31)). g-outer MFMA ordering exposes
// early-gate VALU under later-gate MFMAs. gx is gate-interleaved: ONE dwordx2 gq load/step
// (88 VGPR, ~375us). ONE raw s_barrier per step, lgkm-only drain.
__global__ __launch_bounds__(512, 2) void k_lstm(const unsigned char* __restrict__ w8_all,
                                                 const unsigned short* __restrict__ gx_all,
                                                 unsigned short* __restrict__ hcat) {
    const int d = blockIdx.x >> 5, bg = blockIdx.x & 31;
    const int tid = threadIdx.x, w = tid >> 6, l = tid & 63, quad = l >> 4, col = l & 15;
    const unsigned char* W = w8_all + (size_t)d * 262144;
    const unsigned short* G = gx_all + (size_t)d * 33554432;
    __shared__ __align__(16) unsigned char hld[2][2][288]; // 1,152 B  h fp8 [buf][batch][unit]

    // B-fragments (W): Wb[g][nt][kt] holds W[256g + 32w + 16nt + col][kt*128 + quad*32 .. +31]
    int8v Wb[4][2][2];
    #pragma unroll
    for (int g = 0; g < 4; ++g)
        #pragma unroll
        for (int nt = 0; nt < 2; ++nt)
            #pragma unroll
            for (int kt = 0; kt < 2; ++kt)
                Wb[g][nt][kt] = *(const int8v*)(W + (size_t)(256 * g + 32 * w + 16 * nt + col) * 256
                                                + kt * 128 + quad * 32);
    for (int i = tid; i < 288; i += 512) ((unsigned int*)hld)[i] = 0;

    const int b = l >> 5, u = 32 * w + (l & 31);           // this lane's (batch, unit)
    const int bglob = 2 * bg + b;
    const int nts = quad & 1;                              // nt select for z extraction
    const int hsel = (l >> 3) & 1;                         // batch block for A-fragment rows
    float cst = 0.f;
    const long gstep = d ? -65536 : 65536;                 // shorts per t in gx
    const long hstep = d ? -32768 : 32768;                 // shorts per t in hcat
    const unsigned short* gp = G + ((size_t)((d ? 511 : 0) * 64 + bglob) * 1024 + u * 4);
    unsigned short* hp = hcat + ((size_t)((d ? 511 : 0) * 64 + bglob) * 512 + d * 256 + u);
    uint2 gq = *(const uint2*)gp;                          // gates i,f (x) g,o (y) for this unit
    gp += gstep;
    __syncthreads();

    #pragma clang loop unroll(disable)
    for (int step = 0; step < 512; ++step) {
        const int cur = step & 1;
        // ---- MFMA phase: A = h (row blocks of 8 per batch), B = W; g-outer for early z ----
        int8v Af[2];
        #pragma unroll
        for (int kt = 0; kt < 2; ++kt)
            Af[kt] = *(const int8v*)(&hld[cur][hsel][kt * 128 + quad * 32]);
        float z[4];
        #pragma unroll
        for (int g = 0; g < 4; ++g) {
            floatx4 c0 = (floatx4){0.f, 0.f, 0.f, 0.f};
            floatx4 c1 = (floatx4){0.f, 0.f, 0.f, 0.f};
            #pragma unroll
            for (int kt = 0; kt < 2; ++kt) {
                c0 = __builtin_amdgcn_mfma_scale_f32_16x16x128_f8f6f4(
                    Af[kt], Wb[g][0][kt], c0, 0, 0, 0, 0x7f7f7f7f, 0, 0x7f7f7f7f);
                c1 = __builtin_amdgcn_mfma_scale_f32_16x16x128_f8f6f4(
                    Af[kt], Wb[g][1][kt], c1, 0, 0, 0, 0x7f7f7f7f, 0, 0x7f7f7f7f);
            }
            z[g] = nts ? c1[0] : c0[0];
        }
        // ---- gate phase: fully distributed, one (batch,unit) per lane ----
        float vi = z[0] + asf(gq.x << 16);
        float vf = z[1] + asf(gq.x & 0xffff0000u);
        float vg = z[2] + asf(gq.y << 16);
        float vo = z[3] + asf(gq.y & 0xffff0000u);
        // prefetch next step's gx (stays in flight across the raw barrier)
        gq = *(const uint2*)gp;
        gp += gstep;
        float cc = sigm(vf) * cst + sigm(vi) * tanh_(vg);
        cst = cc;
        float hf = sigm(vo) * tanh_(cc);
        *hp = f2bf_rz(hf);
        hp += hstep;
        int pk = __builtin_amdgcn_cvt_pk_fp8_f32(hf, hf, 0, false);
        hld[cur ^ 1][b][u] = (unsigned char)(pk & 0xff);
        // ---- step boundary: LDS-only drain + raw barrier (no vmcnt drain) ----
        __builtin_amdgcn_sched_barrier(0);
        asm volatile("s_waitcnt lgkmcnt(0)");
        __builtin_amdgcn_sched_barrier(0);
        __builtin_amdgcn_s_barrier();
        __builtin_amdgcn_sched_barrier(0);
    }
}

// ---------------- scores = hcat @ w_fc.T + b_fc, fp32 [t][b][32] ----------------
__global__ __launch_bounds__(256, 4) void k_scores(const unsigned short* __restrict__ hcat,
                                                   const unsigned short* __restrict__ wfc,
                                                   const float* __restrict__ bfc,
                                                   float* __restrict__ sc) {
    const int tid = threadIdx.x, w = tid >> 6, l = tid & 63, quad = l >> 4, col = l & 15;
    const int m0 = blockIdx.x * 64 + w * 16;
    floatx4 C0 = (floatx4){0.f, 0.f, 0.f, 0.f}, C1 = C0;
    #pragma unroll
    for (int kt = 0; kt < 16; ++kt) {
        short8 A  = *(const short8*)(hcat + (size_t)(m0 + col) * 512 + kt * 32 + quad * 8);
        short8 B0 = *(const short8*)(wfc + (size_t)col * 512 + kt * 32 + quad * 8);
        short8 B1 = *(const short8*)(wfc + (size_t)(16 + col) * 512 + kt * 32 + quad * 8);
        C0 = __builtin_amdgcn_mfma_f32_16x16x32_bf16(A, B0, C0, 0, 0, 0);
        C1 = __builtin_amdgcn_mfma_f32_16x16x32_bf16(A, B1, C1, 0, 0, 0);
    }
    float b0 = bfc[col], b1 = bfc[16 + col];
    #pragma unroll
    for (int r = 0; r < 4; ++r) {
        int m = m0 + quad * 4 + r;
        sc[(size_t)m * 32 + col] = C0[r] + b0;
        sc[(size_t)m * 32 + 16 + col] = C1[r] + b1;
    }
}

// ---------------- CRF: true path score + forward algorithm, loss += total - true ----------------
// Dynamic-LDS version: the block's ENTIRE score slice (512x32 f32 = 64 KB) + mask (2 KB)
// is preloaded once; the 511-iteration scan then touches ZERO global memory (the old
// per-iter __syncthreads vmcnt(0) drain put ~200-900 cyc of sc/mask load latency on the
// critical path every step). Arithmetic order unchanged -> bit-identical loss.
__global__ __launch_bounds__(1024, 1) void k_crf(const float* __restrict__ sc, const int* __restrict__ tags,
                                                 const int* __restrict__ mask, const float* __restrict__ tr,
                                                 float* __restrict__ out) {
    extern __shared__ __align__(16) char smem[];
    float* scl = (float*)smem;                    // [512*32]  65,536 B
    float* Tm  = scl + 16384;                     // [32][33]   4,224 B
    float* al  = Tm + 1056;                       // [2][32]      256 B
    int*   msk = (int*)(al + 64);                 // [512]      2,048 B   total 72,064 B
    const int b = blockIdx.x, tid = threadIdx.x;
    // ---- preload score slice (4 passes of 1024 x float4) + mask + transition ----
    #pragma unroll
    for (int p = 0; p < 4; ++p) {
        int t = p * 128 + (tid >> 3), seg = (tid & 7) * 4;
        *(float4*)&scl[t * 32 + seg] = *(const float4*)&sc[((size_t)(t * 64 + b)) * 32 + seg];
    }
    if (tid < 512) msk[tid] = mask[b * 512 + tid];
    { int i = tid >> 5, j = tid & 31; Tm[i * 33 + j] = tr[tid]; }
    __syncthreads();
    float trueb = 0.f;
    if (tid < 64) {
        float acc = 0.f; int cnt = 0;
        for (int t = tid; t < 512; t += 64) cnt += msk[t];
        for (int t = tid + 1; t < 512; t += 64) {
            if (msk[t]) {
                int tg = tags[b * 512 + t], tp = tags[b * 512 + t - 1];
                acc += Tm[tp * 33 + tg] + scl[t * 32 + tg];
            }
        }
        #pragma unroll
        for (int m = 1; m < 64; m <<= 1) { acc += __shfl_xor(acc, m); cnt += __shfl_xor(cnt, m); }
        if (tid == 0) {
            int tg0 = tags[b * 512];
            float first = Tm[30 * 33 + tg0] + scl[tg0];
            int lt = tags[b * 512 + cnt - 1];
            trueb = first + acc + Tm[lt * 33 + 31];
        }
    }
    if (tid < 32) al[tid] = Tm[30 * 33 + tid] + scl[tid];
    __syncthreads();
    const int j = tid >> 5, i = tid & 31;
    int cur = 0;
    #pragma clang loop unroll(disable)
    for (int t = 1; t < 512; ++t) {
        float v = al[cur * 32 + i] + Tm[i * 33 + j];
        float mx = v;
        #pragma unroll
        for (int m = 1; m < 32; m <<= 1) mx = fmaxf(mx, __shfl_xor(mx, m));
        float e = __expf(v - mx);
        #pragma unroll
        for (int m = 1; m < 32; m <<= 1) e += __shfl_xor(e, m);
        float nv = mx + __logf(e) + scl[t * 32 + j];
        if (i == 0) al[(cur ^ 1) * 32 + j] = msk[t] ? nv : al[cur * 32 + j];
        __syncthreads();
        cur ^= 1;
    }
    if (tid < 32) {
        float v = al[cur * 32 + tid] + Tm[tid * 33 + 31];
        float mx = v;
        #pragma unroll
        for (int m = 1; m < 32; m <<= 1) mx = fmaxf(mx, __shfl_xor(mx, m));
        float e = __expf(v - mx);
        #pragma unroll
        for (int m = 1; m < 32; m <<= 1) e += __shfl_xor(e, m);
        if (tid == 0) atomicAdd(out, mx + __logf(e) - trueb);
    }
}

extern "C" void kernel_launch(void* const* d_in, const int* in_sizes, int n_in,
                              void* d_out, int out_size, void* d_ws, size_t ws_size,
                              hipStream_t stream) {
    const int* x      = (const int*)d_in[0];
    const int* tags   = (const int*)d_in[1];
    const int* mask   = (const int*)d_in[2];
    const float* emb  = (const float*)d_in[3];
    const float* wihf = (const float*)d_in[4];
    const float* whhf = (const float*)d_in[5];
    const float* bf_  = (const float*)d_in[6];
    const float* wihb = (const float*)d_in[7];
    const float* whhb = (const float*)d_in[8];
    const float* bb_  = (const float*)d_in[9];
    const float* wfc  = (const float*)d_in[10];
    const float* bfc  = (const float*)d_in[11];
    const float* tr   = (const float*)d_in[12];

    char* ws = (char*)d_ws;
    unsigned short* et   = (unsigned short*)(ws);                 //  16,777,216 B
    unsigned short* wbf  = (unsigned short*)(ws + 16777216);      //   1,064,960 B (wih f|b cat, then wfc @ elem 524288)
    unsigned char*  w8   = (unsigned char*)(ws + 17842176);      //     524,288 B (whh f|b fp8)
    unsigned short* gx   = (unsigned short*)(ws + 18366464);      // 134,217,728 B
    unsigned short* hcat = (unsigned short*)(ws + 152584192);     //  33,554,432 B
    float* sc            = (float*)(ws + 186138624);              //   4,194,304 B

    static bool attr_set = false;
    if (!attr_set) {
        hipFuncSetAttribute((const void*)k_crf, hipFuncAttributeMaxDynamicSharedMemorySize, 72064);
        attr_set = true;
    }

    hipMemsetAsync(d_out, 0, sizeof(float), stream);
    k_prep<<<7200, 256, 0, stream>>>(x, emb, et, wihf, wihb, wfc, wbf, whhf, whhb, w8);
    dim3 g2(256, 16);
    k_gx<<<g2, 256, 0, stream>>>(et, wbf, bf_, bb_, gx);
    k_lstm<<<64, 512, 0, stream>>>(w8, gx, hcat);
    k_scores<<<512, 256, 0, stream>>>(hcat, wbf + 524288, bfc, sc);
    k_crf<<<64, 1024, 72064, stream>>>(sc, tags, mask, tr, (float*)d_out);
}